// Round 1
// baseline (631.173 us; speedup 1.0000x reference)
//
#include <hip/hip_runtime.h>

#define N_NODES 100000
#define N_EDGES 1000000
#define C_IN 128
#define C_HID 64
#define C_OUT 32

// ---------------------------------------------------------------------------
// Edge-index normalization: reference says int64, harness docs say int32.
// Detect at runtime: int64 little-endian => high dwords (odd int32 indices)
// are all zero (values < 100000). Normalize into int32 src[]/dst[].
// ---------------------------------------------------------------------------
__global__ __launch_bounds__(64) void k_detect(const unsigned int* __restrict__ ei,
                                               int* __restrict__ flag) {
    if (threadIdx.x == 0 && blockIdx.x == 0) {
        int is64 = 1;
        for (int i = 0; i < 64; ++i)
            if (ei[2 * i + 1] != 0u) { is64 = 0; break; }
        *flag = is64;
    }
}

__global__ __launch_bounds__(256) void k_edges(const unsigned int* __restrict__ ei,
                                               const int* __restrict__ flag,
                                               int* __restrict__ src,
                                               int* __restrict__ dst) {
    int e = blockIdx.x * 256 + threadIdx.x;
    if (e >= N_EDGES) return;
    if (*flag) {  // int64 storage: low dword of element i at int32 index 2i
        src[e] = (int)ei[2 * (size_t)e];
        dst[e] = (int)ei[2 * ((size_t)N_EDGES + e)];
    } else {      // int32 storage
        src[e] = (int)ei[e];
        dst[e] = (int)ei[(size_t)N_EDGES + e];
    }
}

// ---------------------------------------------------------------------------
// Degree (dst-based, as in reference) and dinv = rsqrt(deg + 1 self-loop)
// ---------------------------------------------------------------------------
__global__ __launch_bounds__(256) void k_deg(const int* __restrict__ dst,
                                             int* __restrict__ deg) {
    int e = blockIdx.x * 256 + threadIdx.x;
    if (e < N_EDGES) atomicAdd(&deg[dst[e]], 1);
}

__global__ __launch_bounds__(256) void k_dinv(const int* __restrict__ deg,
                                              float* __restrict__ dinv) {
    int i = blockIdx.x * 256 + threadIdx.x;
    if (i < N_NODES) dinv[i] = rsqrtf((float)deg[i] + 1.0f);
}

// ---------------------------------------------------------------------------
// GEMM1: hs1[n][c] = (x[n][:] @ W1)[c] * dinv[n]    (128 -> 64)
// W1 (32 KB) staged in LDS once per block; block loops row-tiles (amortize).
// LDS read w[k*64+c]: lanes c=0..63 -> 2 lanes/bank = free on gfx950.
// ---------------------------------------------------------------------------
__global__ __launch_bounds__(256) void k_gemm1(const float* __restrict__ x,
                                               const float* __restrict__ W1,
                                               const float* __restrict__ dinv,
                                               float* __restrict__ hs1) {
    __shared__ float w[C_IN * C_HID];
    for (int i = threadIdx.x; i < C_IN * C_HID; i += 256) w[i] = W1[i];
    __syncthreads();
    const int NT = N_NODES / 4;       // 4 rows per tile (1 row per wave)
    const int c = threadIdx.x & 63;
    const int rsub = threadIdx.x >> 6;
    for (int tile = blockIdx.x; tile < NT; tile += gridDim.x) {
        int row = tile * 4 + rsub;
        const float4* xr = reinterpret_cast<const float4*>(x + (size_t)row * C_IN);
        float acc = 0.f;
#pragma unroll
        for (int k4 = 0; k4 < C_IN / 4; ++k4) {
            float4 xv = xr[k4];  // wave-uniform broadcast load
            acc = fmaf(xv.x, w[(k4 * 4 + 0) * C_HID + c], acc);
            acc = fmaf(xv.y, w[(k4 * 4 + 1) * C_HID + c], acc);
            acc = fmaf(xv.z, w[(k4 * 4 + 2) * C_HID + c], acc);
            acc = fmaf(xv.w, w[(k4 * 4 + 3) * C_HID + c], acc);
        }
        hs1[(size_t)row * C_HID + c] = acc * dinv[row];
    }
}

// ---------------------------------------------------------------------------
// Scatter1: agg1[dst][c] += hs1[src][c]; 64 lanes = 64 channels per edge.
// unsafeAtomicAdd -> HW global_atomic_add_f32 (no CAS loop).
// ---------------------------------------------------------------------------
__global__ __launch_bounds__(256) void k_scatter1(const int* __restrict__ src,
                                                  const int* __restrict__ dst,
                                                  const float* __restrict__ hs1,
                                                  float* __restrict__ agg1) {
    int e = blockIdx.x * 4 + (threadIdx.x >> 6);
    int c = threadIdx.x & 63;
    int s = src[e], d = dst[e];
    unsafeAtomicAdd(&agg1[(size_t)d * C_HID + c], hs1[(size_t)s * C_HID + c]);
}

// ---------------------------------------------------------------------------
// Epilogue1: y1 = relu(dinv*(agg1+hs1) + b1), written in place over agg1.
// ---------------------------------------------------------------------------
__global__ __launch_bounds__(256) void k_epi1(const float4* __restrict__ agg1,
                                              const float4* __restrict__ hs1,
                                              const float* __restrict__ dinv,
                                              const float* __restrict__ b1,
                                              float4* __restrict__ y1) {
    int i = blockIdx.x * 256 + threadIdx.x;  // over N * 16 float4s
    if (i >= N_NODES * (C_HID / 4)) return;
    int n = i >> 4;
    int c0 = (i & 15) * 4;
    float di = dinv[n];
    float4 a = agg1[i], h = hs1[i];
    float4 r;
    r.x = fmaxf(fmaf(di, a.x + h.x, b1[c0 + 0]), 0.f);
    r.y = fmaxf(fmaf(di, a.y + h.y, b1[c0 + 1]), 0.f);
    r.z = fmaxf(fmaf(di, a.z + h.z, b1[c0 + 2]), 0.f);
    r.w = fmaxf(fmaf(di, a.w + h.w, b1[c0 + 3]), 0.f);
    y1[i] = r;
}

// ---------------------------------------------------------------------------
// GEMM2: hs2[n][c] = (y1[n][:] @ W2)[c] * dinv[n]    (64 -> 32)
// ---------------------------------------------------------------------------
__global__ __launch_bounds__(256) void k_gemm2(const float* __restrict__ y1,
                                               const float* __restrict__ W2,
                                               const float* __restrict__ dinv,
                                               float* __restrict__ hs2) {
    __shared__ float w[C_HID * C_OUT];
    for (int i = threadIdx.x; i < C_HID * C_OUT; i += 256) w[i] = W2[i];
    __syncthreads();
    const int NT = N_NODES / 8;       // 8 rows per tile (2 rows per wave)
    const int c = threadIdx.x & 31;
    const int rsub = threadIdx.x >> 5;
    for (int tile = blockIdx.x; tile < NT; tile += gridDim.x) {
        int row = tile * 8 + rsub;
        const float4* yr = reinterpret_cast<const float4*>(y1 + (size_t)row * C_HID);
        float acc = 0.f;
#pragma unroll
        for (int k4 = 0; k4 < C_HID / 4; ++k4) {
            float4 yv = yr[k4];
            acc = fmaf(yv.x, w[(k4 * 4 + 0) * C_OUT + c], acc);
            acc = fmaf(yv.y, w[(k4 * 4 + 1) * C_OUT + c], acc);
            acc = fmaf(yv.z, w[(k4 * 4 + 2) * C_OUT + c], acc);
            acc = fmaf(yv.w, w[(k4 * 4 + 3) * C_OUT + c], acc);
        }
        hs2[(size_t)row * C_OUT + c] = acc * dinv[row];
    }
}

__global__ __launch_bounds__(256) void k_scatter2(const int* __restrict__ src,
                                                  const int* __restrict__ dst,
                                                  const float* __restrict__ hs2,
                                                  float* __restrict__ agg2) {
    int e = blockIdx.x * 8 + (threadIdx.x >> 5);
    int c = threadIdx.x & 31;
    int s = src[e], d = dst[e];
    unsafeAtomicAdd(&agg2[(size_t)d * C_OUT + c], hs2[(size_t)s * C_OUT + c]);
}

// Epilogue2: out = dinv*(agg2+hs2) + b2 (no relu), straight to d_out.
__global__ __launch_bounds__(256) void k_epi2(const float4* __restrict__ agg2,
                                              const float4* __restrict__ hs2,
                                              const float* __restrict__ dinv,
                                              const float* __restrict__ b2,
                                              float4* __restrict__ out) {
    int i = blockIdx.x * 256 + threadIdx.x;  // over N * 8 float4s
    if (i >= N_NODES * (C_OUT / 4)) return;
    int n = i >> 3;
    int c0 = (i & 7) * 4;
    float di = dinv[n];
    float4 a = agg2[i], h = hs2[i];
    float4 r;
    r.x = fmaf(di, a.x + h.x, b2[c0 + 0]);
    r.y = fmaf(di, a.y + h.y, b2[c0 + 1]);
    r.z = fmaf(di, a.z + h.z, b2[c0 + 2]);
    r.w = fmaf(di, a.w + h.w, b2[c0 + 3]);
    out[i] = r;
}

extern "C" void kernel_launch(void* const* d_in, const int* in_sizes, int n_in,
                              void* d_out, int out_size, void* d_ws, size_t ws_size,
                              hipStream_t stream) {
    const float* x  = (const float*)d_in[0];
    const unsigned int* ei = (const unsigned int*)d_in[1];
    const float* W1 = (const float*)d_in[2];
    const float* b1 = (const float*)d_in[3];
    const float* W2 = (const float*)d_in[4];
    const float* b2 = (const float*)d_in[5];
    float* out = (float*)d_out;

    // Workspace carve-up (~86 MB total)
    char* ws = (char*)d_ws;
    size_t off = 0;
    auto take = [&](size_t bytes) {
        char* p = ws + off;
        off += (bytes + 255) & ~(size_t)255;
        return p;
    };
    int*   flag = (int*)  take(256);
    int*   src  = (int*)  take((size_t)N_EDGES * 4);
    int*   dst  = (int*)  take((size_t)N_EDGES * 4);
    int*   deg  = (int*)  take((size_t)N_NODES * 4);
    float* dinv = (float*)take((size_t)N_NODES * 4);
    float* hs1  = (float*)take((size_t)N_NODES * C_HID * 4);
    float* agg1 = (float*)take((size_t)N_NODES * C_HID * 4);
    float* hs2  = (float*)take((size_t)N_NODES * C_OUT * 4);
    float* agg2 = (float*)take((size_t)N_NODES * C_OUT * 4);

    // Edge normalization + degrees
    k_detect<<<1, 64, 0, stream>>>(ei, flag);
    k_edges<<<(N_EDGES + 255) / 256, 256, 0, stream>>>(ei, flag, src, dst);
    hipMemsetAsync(deg, 0, (size_t)N_NODES * 4, stream);
    k_deg<<<(N_EDGES + 255) / 256, 256, 0, stream>>>(dst, deg);
    k_dinv<<<(N_NODES + 255) / 256, 256, 0, stream>>>(deg, dinv);

    // Layer 1
    k_gemm1<<<2048, 256, 0, stream>>>(x, W1, dinv, hs1);
    hipMemsetAsync(agg1, 0, (size_t)N_NODES * C_HID * 4, stream);
    k_scatter1<<<N_EDGES / 4, 256, 0, stream>>>(src, dst, hs1, agg1);
    k_epi1<<<(N_NODES * (C_HID / 4) + 255) / 256, 256, 0, stream>>>(
        (const float4*)agg1, (const float4*)hs1, dinv, b1, (float4*)agg1);

    // Layer 2 (y1 lives in agg1's buffer)
    k_gemm2<<<2048, 256, 0, stream>>>((const float*)agg1, W2, dinv, hs2);
    hipMemsetAsync(agg2, 0, (size_t)N_NODES * C_OUT * 4, stream);
    k_scatter2<<<N_EDGES / 8, 256, 0, stream>>>(src, dst, hs2, agg2);
    k_epi2<<<(N_NODES * (C_OUT / 4) + 255) / 256, 256, 0, stream>>>(
        (const float4*)agg2, (const float4*)hs2, dinv, b2, (float4*)out);
}

// Round 2
// 443.748 us; speedup vs baseline: 1.4224x; 1.4224x over previous
//
#include <hip/hip_runtime.h>

#define N_NODES 100000
#define N_EDGES 1000000
#define C_IN 128
#define C_HID 64
#define C_OUT 32
#define NB1 ((N_NODES + 255) / 256)   // 391 scan blocks

// ---------------------------------------------------------------------------
// Edge-index dtype detection (int64 vs int32 storage).
// ---------------------------------------------------------------------------
__global__ __launch_bounds__(64) void k_detect(const unsigned int* __restrict__ ei,
                                               int* __restrict__ flag) {
    if (threadIdx.x == 0 && blockIdx.x == 0) {
        int is64 = 1;
        for (int i = 0; i < 64; ++i)
            if (ei[2 * i + 1] != 0u) { is64 = 0; break; }
        *flag = is64;
    }
}

// Normalize edges to int32 src/dst AND histogram dst degrees in one pass.
__global__ __launch_bounds__(256) void k_edges(const unsigned int* __restrict__ ei,
                                               const int* __restrict__ flag,
                                               int* __restrict__ src,
                                               int* __restrict__ dst,
                                               int* __restrict__ deg) {
    int e = blockIdx.x * 256 + threadIdx.x;
    if (e >= N_EDGES) return;
    int s, d;
    if (*flag) {
        s = (int)ei[2 * (size_t)e];
        d = (int)ei[2 * ((size_t)N_EDGES + e)];
    } else {
        s = (int)ei[e];
        d = (int)ei[(size_t)N_EDGES + e];
    }
    src[e] = s;
    dst[e] = d;
    atomicAdd(&deg[d], 1);
}

// ---------------------------------------------------------------------------
// 3-kernel exclusive prefix scan of deg -> rowstart; also dinv = rsqrt(deg+1).
// ---------------------------------------------------------------------------
__global__ __launch_bounds__(256) void k_scan1(const int* __restrict__ deg,
                                               int* __restrict__ rowstart,
                                               int* __restrict__ blksum,
                                               float* __restrict__ dinv) {
    __shared__ int sm[256];
    int i = blockIdx.x * 256 + threadIdx.x;
    int v = (i < N_NODES) ? deg[i] : 0;
    if (i < N_NODES) dinv[i] = rsqrtf((float)v + 1.0f);
    sm[threadIdx.x] = v;
    __syncthreads();
    for (int o = 1; o < 256; o <<= 1) {
        int t = (threadIdx.x >= o) ? sm[threadIdx.x - o] : 0;
        __syncthreads();
        sm[threadIdx.x] += t;
        __syncthreads();
    }
    if (i < N_NODES) rowstart[i] = sm[threadIdx.x] - v;   // exclusive, block-local
    if (threadIdx.x == 255) blksum[blockIdx.x] = sm[255];
}

__global__ __launch_bounds__(512) void k_scan2(const int* __restrict__ blksum,
                                               int* __restrict__ blkoff) {
    __shared__ int sm[512];
    int v = (threadIdx.x < NB1) ? blksum[threadIdx.x] : 0;
    sm[threadIdx.x] = v;
    __syncthreads();
    for (int o = 1; o < 512; o <<= 1) {
        int t = (threadIdx.x >= o) ? sm[threadIdx.x - o] : 0;
        __syncthreads();
        sm[threadIdx.x] += t;
        __syncthreads();
    }
    if (threadIdx.x < NB1) blkoff[threadIdx.x] = sm[threadIdx.x] - v;  // exclusive
}

__global__ __launch_bounds__(256) void k_scan3(int* __restrict__ rowstart,
                                               const int* __restrict__ blkoff,
                                               int* __restrict__ cursor) {
    int i = blockIdx.x * 256 + threadIdx.x;
    if (i < N_NODES) {
        int r = rowstart[i] + blkoff[i >> 8];
        rowstart[i] = r;
        cursor[i] = r;
    }
    if (i == 0) rowstart[N_NODES] = N_EDGES;
}

// Counting-sort scatter: esrc[] = src sorted by dst (order within node free).
__global__ __launch_bounds__(256) void k_fill(const int* __restrict__ src,
                                              const int* __restrict__ dst,
                                              int* __restrict__ cursor,
                                              int* __restrict__ esrc) {
    int e = blockIdx.x * 256 + threadIdx.x;
    if (e >= N_EDGES) return;
    int p = atomicAdd(&cursor[dst[e]], 1);
    esrc[p] = src[e];
}

// ---------------------------------------------------------------------------
// GEMM1: hs1[n][c] = (x[n][:] @ W1)[c] * dinv[n]    (128 -> 64)
// ---------------------------------------------------------------------------
__global__ __launch_bounds__(256) void k_gemm1(const float* __restrict__ x,
                                               const float* __restrict__ W1,
                                               const float* __restrict__ dinv,
                                               float* __restrict__ hs1) {
    __shared__ float w[C_IN * C_HID];
    for (int i = threadIdx.x; i < C_IN * C_HID; i += 256) w[i] = W1[i];
    __syncthreads();
    const int NT = N_NODES / 4;
    const int c = threadIdx.x & 63;
    const int rsub = threadIdx.x >> 6;
    for (int tile = blockIdx.x; tile < NT; tile += gridDim.x) {
        int row = tile * 4 + rsub;
        const float4* xr = reinterpret_cast<const float4*>(x + (size_t)row * C_IN);
        float acc = 0.f;
#pragma unroll
        for (int k4 = 0; k4 < C_IN / 4; ++k4) {
            float4 xv = xr[k4];
            acc = fmaf(xv.x, w[(k4 * 4 + 0) * C_HID + c], acc);
            acc = fmaf(xv.y, w[(k4 * 4 + 1) * C_HID + c], acc);
            acc = fmaf(xv.z, w[(k4 * 4 + 2) * C_HID + c], acc);
            acc = fmaf(xv.w, w[(k4 * 4 + 3) * C_HID + c], acc);
        }
        hs1[(size_t)row * C_HID + c] = acc * dinv[row];
    }
}

// ---------------------------------------------------------------------------
// Agg1 (+fused epilogue): y1[n] = relu(dinv[n]*(Σ_in hs1[src] + hs1[n]) + b1)
// One wave per node; lane = channel (64). 2-edge unroll for load ILP.
// ---------------------------------------------------------------------------
__global__ __launch_bounds__(256) void k_agg1(const int* __restrict__ rowstart,
                                              const int* __restrict__ esrc,
                                              const float* __restrict__ hs1,
                                              const float* __restrict__ dinv,
                                              const float* __restrict__ b1,
                                              float* __restrict__ y1) {
    int node = blockIdx.x * 4 + (threadIdx.x >> 6);
    int c = threadIdx.x & 63;
    int beg = rowstart[node], end = rowstart[node + 1];
    float acc = hs1[(size_t)node * C_HID + c];   // self-loop term
    int j = beg;
    for (; j + 1 < end; j += 2) {
        int s0 = esrc[j], s1 = esrc[j + 1];
        float v0 = hs1[(size_t)s0 * C_HID + c];
        float v1 = hs1[(size_t)s1 * C_HID + c];
        acc += v0 + v1;
    }
    if (j < end) acc += hs1[(size_t)esrc[j] * C_HID + c];
    y1[(size_t)node * C_HID + c] = fmaxf(fmaf(dinv[node], acc, b1[c]), 0.f);
}

// ---------------------------------------------------------------------------
// GEMM2: hs2[n][c] = (y1[n][:] @ W2)[c] * dinv[n]    (64 -> 32)
// ---------------------------------------------------------------------------
__global__ __launch_bounds__(256) void k_gemm2(const float* __restrict__ y1,
                                               const float* __restrict__ W2,
                                               const float* __restrict__ dinv,
                                               float* __restrict__ hs2) {
    __shared__ float w[C_HID * C_OUT];
    for (int i = threadIdx.x; i < C_HID * C_OUT; i += 256) w[i] = W2[i];
    __syncthreads();
    const int NT = N_NODES / 8;
    const int c = threadIdx.x & 31;
    const int rsub = threadIdx.x >> 5;
    for (int tile = blockIdx.x; tile < NT; tile += gridDim.x) {
        int row = tile * 8 + rsub;
        const float4* yr = reinterpret_cast<const float4*>(y1 + (size_t)row * C_HID);
        float acc = 0.f;
#pragma unroll
        for (int k4 = 0; k4 < C_HID / 4; ++k4) {
            float4 yv = yr[k4];
            acc = fmaf(yv.x, w[(k4 * 4 + 0) * C_OUT + c], acc);
            acc = fmaf(yv.y, w[(k4 * 4 + 1) * C_OUT + c], acc);
            acc = fmaf(yv.z, w[(k4 * 4 + 2) * C_OUT + c], acc);
            acc = fmaf(yv.w, w[(k4 * 4 + 3) * C_OUT + c], acc);
        }
        hs2[(size_t)row * C_OUT + c] = acc * dinv[row];
    }
}

// Agg2 (+fused epilogue, no relu): out = dinv*(Σ hs2[src] + hs2[n]) + b2
// Two nodes per wave; lane&31 = channel (32).
__global__ __launch_bounds__(256) void k_agg2(const int* __restrict__ rowstart,
                                              const int* __restrict__ esrc,
                                              const float* __restrict__ hs2,
                                              const float* __restrict__ dinv,
                                              const float* __restrict__ b2,
                                              float* __restrict__ out) {
    int node = blockIdx.x * 8 + (threadIdx.x >> 5);
    int c = threadIdx.x & 31;
    int beg = rowstart[node], end = rowstart[node + 1];
    float acc = hs2[(size_t)node * C_OUT + c];
    int j = beg;
    for (; j + 1 < end; j += 2) {
        int s0 = esrc[j], s1 = esrc[j + 1];
        float v0 = hs2[(size_t)s0 * C_OUT + c];
        float v1 = hs2[(size_t)s1 * C_OUT + c];
        acc += v0 + v1;
    }
    if (j < end) acc += hs2[(size_t)esrc[j] * C_OUT + c];
    out[(size_t)node * C_OUT + c] = fmaf(dinv[node], acc, b2[c]);
}

extern "C" void kernel_launch(void* const* d_in, const int* in_sizes, int n_in,
                              void* d_out, int out_size, void* d_ws, size_t ws_size,
                              hipStream_t stream) {
    const float* x  = (const float*)d_in[0];
    const unsigned int* ei = (const unsigned int*)d_in[1];
    const float* W1 = (const float*)d_in[2];
    const float* b1 = (const float*)d_in[3];
    const float* W2 = (const float*)d_in[4];
    const float* b2 = (const float*)d_in[5];
    float* out = (float*)d_out;

    char* ws = (char*)d_ws;
    size_t off = 0;
    auto take = [&](size_t bytes) {
        char* p = ws + off;
        off += (bytes + 255) & ~(size_t)255;
        return p;
    };
    int*   flag     = (int*)  take(256);
    int*   src      = (int*)  take((size_t)N_EDGES * 4);
    int*   dst      = (int*)  take((size_t)N_EDGES * 4);
    int*   esrc     = (int*)  take((size_t)N_EDGES * 4);
    int*   deg      = (int*)  take((size_t)N_NODES * 4);
    int*   rowstart = (int*)  take((size_t)(N_NODES + 1) * 4);
    int*   cursor   = (int*)  take((size_t)N_NODES * 4);
    int*   blksum   = (int*)  take((size_t)NB1 * 4);
    int*   blkoff   = (int*)  take((size_t)NB1 * 4);
    float* dinv     = (float*)take((size_t)N_NODES * 4);
    float* hs1      = (float*)take((size_t)N_NODES * C_HID * 4);
    float* y1       = (float*)take((size_t)N_NODES * C_HID * 4);
    float* hs2      = (float*)take((size_t)N_NODES * C_OUT * 4);

    // Edge normalize + degree histogram
    k_detect<<<1, 64, 0, stream>>>(ei, flag);
    hipMemsetAsync(deg, 0, (size_t)N_NODES * 4, stream);
    k_edges<<<(N_EDGES + 255) / 256, 256, 0, stream>>>(ei, flag, src, dst, deg);

    // CSR build: scan degrees, scatter src by dst
    k_scan1<<<NB1, 256, 0, stream>>>(deg, rowstart, blksum, dinv);
    k_scan2<<<1, 512, 0, stream>>>(blksum, blkoff);
    k_scan3<<<NB1, 256, 0, stream>>>(rowstart, blkoff, cursor);
    k_fill<<<(N_EDGES + 255) / 256, 256, 0, stream>>>(src, dst, cursor, esrc);

    // Layer 1
    k_gemm1<<<2048, 256, 0, stream>>>(x, W1, dinv, hs1);
    k_agg1<<<N_NODES / 4, 256, 0, stream>>>(rowstart, esrc, hs1, dinv, b1, y1);

    // Layer 2
    k_gemm2<<<2048, 256, 0, stream>>>(y1, W2, dinv, hs2);
    k_agg2<<<N_NODES / 8, 256, 0, stream>>>(rowstart, esrc, hs2, dinv, b2, out);
}

// Round 3
// 431.994 us; speedup vs baseline: 1.4611x; 1.0272x over previous
//
#include <hip/hip_runtime.h>

#define N_NODES 100000
#define N_EDGES 1000000
#define C_IN 128
#define C_HID 64
#define C_OUT 32
#define NB1 ((N_NODES + 255) / 256)   // 391 scan blocks
#define NTILE (N_NODES / 32)          // 3125 gemm tiles (32 rows each)

// ---------------------------------------------------------------------------
// Edge-index dtype detection (int64 vs int32 storage).
// ---------------------------------------------------------------------------
__global__ __launch_bounds__(64) void k_detect(const unsigned int* __restrict__ ei,
                                               int* __restrict__ flag) {
    if (threadIdx.x == 0 && blockIdx.x == 0) {
        int is64 = 1;
        for (int i = 0; i < 64; ++i)
            if (ei[2 * i + 1] != 0u) { is64 = 0; break; }
        *flag = is64;
    }
}

// Histogram dst degrees straight from edge_index (no staging arrays).
__global__ __launch_bounds__(256) void k_hist(const unsigned int* __restrict__ ei,
                                              const int* __restrict__ flag,
                                              int* __restrict__ deg) {
    int e = blockIdx.x * 256 + threadIdx.x;
    if (e >= N_EDGES) return;
    int d;
    if (*flag) {  // int64: element i = 8B; take low dword via coalesced int2
        d = ((const int2*)ei)[(size_t)N_EDGES + e].x;
    } else {
        d = (int)ei[(size_t)N_EDGES + e];
    }
    atomicAdd(&deg[d], 1);
}

// ---------------------------------------------------------------------------
// 3-kernel exclusive prefix scan of deg -> rowstart; also dinv = rsqrt(deg+1).
// ---------------------------------------------------------------------------
__global__ __launch_bounds__(256) void k_scan1(const int* __restrict__ deg,
                                               int* __restrict__ rowstart,
                                               int* __restrict__ blksum,
                                               float* __restrict__ dinv) {
    __shared__ int sm[256];
    int i = blockIdx.x * 256 + threadIdx.x;
    int v = (i < N_NODES) ? deg[i] : 0;
    if (i < N_NODES) dinv[i] = rsqrtf((float)v + 1.0f);
    sm[threadIdx.x] = v;
    __syncthreads();
    for (int o = 1; o < 256; o <<= 1) {
        int t = (threadIdx.x >= o) ? sm[threadIdx.x - o] : 0;
        __syncthreads();
        sm[threadIdx.x] += t;
        __syncthreads();
    }
    if (i < N_NODES) rowstart[i] = sm[threadIdx.x] - v;   // exclusive, block-local
    if (threadIdx.x == 255) blksum[blockIdx.x] = sm[255];
}

__global__ __launch_bounds__(512) void k_scan2(const int* __restrict__ blksum,
                                               int* __restrict__ blkoff) {
    __shared__ int sm[512];
    int v = (threadIdx.x < NB1) ? blksum[threadIdx.x] : 0;
    sm[threadIdx.x] = v;
    __syncthreads();
    for (int o = 1; o < 512; o <<= 1) {
        int t = (threadIdx.x >= o) ? sm[threadIdx.x - o] : 0;
        __syncthreads();
        sm[threadIdx.x] += t;
        __syncthreads();
    }
    if (threadIdx.x < NB1) blkoff[threadIdx.x] = sm[threadIdx.x] - v;  // exclusive
}

__global__ __launch_bounds__(256) void k_scan3(int* __restrict__ rowstart,
                                               const int* __restrict__ blkoff,
                                               int* __restrict__ cursor) {
    int i = blockIdx.x * 256 + threadIdx.x;
    if (i < N_NODES) {
        int r = rowstart[i] + blkoff[i >> 8];
        rowstart[i] = r;
        cursor[i] = r;
    }
    if (i == 0) rowstart[N_NODES] = N_EDGES;
}

// Counting-sort scatter: esrc[] = src sorted by dst. Reads ei directly.
__global__ __launch_bounds__(256) void k_fill(const unsigned int* __restrict__ ei,
                                              const int* __restrict__ flag,
                                              int* __restrict__ cursor,
                                              int* __restrict__ esrc) {
    int e = blockIdx.x * 256 + threadIdx.x;
    if (e >= N_EDGES) return;
    int s, d;
    if (*flag) {
        s = ((const int2*)ei)[e].x;
        d = ((const int2*)ei)[(size_t)N_EDGES + e].x;
    } else {
        s = (int)ei[e];
        d = (int)ei[(size_t)N_EDGES + e];
    }
    int p = atomicAdd(&cursor[d], 1);
    esrc[p] = s;
}

// ---------------------------------------------------------------------------
// GEMM1: hs1[n][c] = (x[n][:] @ W1)[c] * dinv[n]    (128 -> 64)
// Wave = 8 rows x 64 channels (lane=channel). 8 independent accumulators
// per lane break the dependent-FMA-chain stall (R2: VALUBusy 21%).
// Block = 4 waves = 32 rows; one tile per block.
// ---------------------------------------------------------------------------
__global__ __launch_bounds__(256) void k_gemm1(const float* __restrict__ x,
                                               const float* __restrict__ W1,
                                               const float* __restrict__ dinv,
                                               float* __restrict__ hs1) {
    __shared__ float w[C_IN * C_HID];
    for (int i = threadIdx.x; i < C_IN * C_HID; i += 256) w[i] = W1[i];
    __syncthreads();
    const int c = threadIdx.x & 63;
    const int wid = threadIdx.x >> 6;
    const int row0 = blockIdx.x * 32 + wid * 8;
    const float4* x4 = reinterpret_cast<const float4*>(x);
    float acc[8] = {0.f, 0.f, 0.f, 0.f, 0.f, 0.f, 0.f, 0.f};
    for (int k4 = 0; k4 < C_IN / 4; ++k4) {
        float4 xv[8];
#pragma unroll
        for (int r = 0; r < 8; ++r)
            xv[r] = x4[(size_t)(row0 + r) * (C_IN / 4) + k4];  // broadcast load
        float w0 = w[(k4 * 4 + 0) * C_HID + c];
        float w1 = w[(k4 * 4 + 1) * C_HID + c];
        float w2 = w[(k4 * 4 + 2) * C_HID + c];
        float w3 = w[(k4 * 4 + 3) * C_HID + c];
#pragma unroll
        for (int r = 0; r < 8; ++r) {
            acc[r] = fmaf(xv[r].x, w0, acc[r]);
            acc[r] = fmaf(xv[r].y, w1, acc[r]);
            acc[r] = fmaf(xv[r].z, w2, acc[r]);
            acc[r] = fmaf(xv[r].w, w3, acc[r]);
        }
    }
#pragma unroll
    for (int r = 0; r < 8; ++r)
        hs1[(size_t)(row0 + r) * C_HID + c] = acc[r] * dinv[row0 + r];
}

// ---------------------------------------------------------------------------
// Agg1 (+fused epilogue): y1[n] = relu(dinv[n]*(Σ_in hs1[src] + hs1[n]) + b1)
// One wave per node; lane = channel (64). 4-edge unroll for load ILP.
// ---------------------------------------------------------------------------
__global__ __launch_bounds__(256) void k_agg1(const int* __restrict__ rowstart,
                                              const int* __restrict__ esrc,
                                              const float* __restrict__ hs1,
                                              const float* __restrict__ dinv,
                                              const float* __restrict__ b1,
                                              float* __restrict__ y1) {
    int node = blockIdx.x * 4 + (threadIdx.x >> 6);
    int c = threadIdx.x & 63;
    int beg = rowstart[node], end = rowstart[node + 1];
    float acc = hs1[(size_t)node * C_HID + c];   // self-loop term
    int j = beg;
    for (; j + 3 < end; j += 4) {
        int s0 = esrc[j], s1 = esrc[j + 1], s2 = esrc[j + 2], s3 = esrc[j + 3];
        float v0 = hs1[(size_t)s0 * C_HID + c];
        float v1 = hs1[(size_t)s1 * C_HID + c];
        float v2 = hs1[(size_t)s2 * C_HID + c];
        float v3 = hs1[(size_t)s3 * C_HID + c];
        acc += (v0 + v1) + (v2 + v3);
    }
    for (; j < end; ++j) acc += hs1[(size_t)esrc[j] * C_HID + c];
    y1[(size_t)node * C_HID + c] = fmaxf(fmaf(dinv[node], acc, b1[c]), 0.f);
}

// ---------------------------------------------------------------------------
// GEMM2: hs2[n][c] = (y1[n][:] @ W2)[c] * dinv[n]    (64 -> 32)
// Wave = 8 rows x 32 channels: lanes 0-31 rows r0..r0+3, lanes 32-63 r0+4..+7.
// 4 accumulators per lane.
// ---------------------------------------------------------------------------
__global__ __launch_bounds__(256) void k_gemm2(const float* __restrict__ y1,
                                               const float* __restrict__ W2,
                                               const float* __restrict__ dinv,
                                               float* __restrict__ hs2) {
    __shared__ float w[C_HID * C_OUT];
    for (int i = threadIdx.x; i < C_HID * C_OUT; i += 256) w[i] = W2[i];
    __syncthreads();
    const int c = threadIdx.x & 31;
    const int h = (threadIdx.x >> 5) & 1;    // which half of the wave
    const int wid = threadIdx.x >> 6;
    const int row0 = blockIdx.x * 32 + wid * 8 + h * 4;
    const float4* y4 = reinterpret_cast<const float4*>(y1);
    float acc[4] = {0.f, 0.f, 0.f, 0.f};
    for (int k4 = 0; k4 < C_HID / 4; ++k4) {
        float4 yv[4];
#pragma unroll
        for (int r = 0; r < 4; ++r)
            yv[r] = y4[(size_t)(row0 + r) * (C_HID / 4) + k4];
        float w0 = w[(k4 * 4 + 0) * C_OUT + c];
        float w1 = w[(k4 * 4 + 1) * C_OUT + c];
        float w2 = w[(k4 * 4 + 2) * C_OUT + c];
        float w3 = w[(k4 * 4 + 3) * C_OUT + c];
#pragma unroll
        for (int r = 0; r < 4; ++r) {
            acc[r] = fmaf(yv[r].x, w0, acc[r]);
            acc[r] = fmaf(yv[r].y, w1, acc[r]);
            acc[r] = fmaf(yv[r].z, w2, acc[r]);
            acc[r] = fmaf(yv[r].w, w3, acc[r]);
        }
    }
#pragma unroll
    for (int r = 0; r < 4; ++r)
        hs2[(size_t)(row0 + r) * C_OUT + c] = acc[r] * dinv[row0 + r];
}

// Agg2 (+fused epilogue, no relu): out = dinv*(Σ hs2[src] + hs2[n]) + b2
__global__ __launch_bounds__(256) void k_agg2(const int* __restrict__ rowstart,
                                              const int* __restrict__ esrc,
                                              const float* __restrict__ hs2,
                                              const float* __restrict__ dinv,
                                              const float* __restrict__ b2,
                                              float* __restrict__ out) {
    int node = blockIdx.x * 8 + (threadIdx.x >> 5);
    int c = threadIdx.x & 31;
    int beg = rowstart[node], end = rowstart[node + 1];
    float acc = hs2[(size_t)node * C_OUT + c];
    int j = beg;
    for (; j + 3 < end; j += 4) {
        int s0 = esrc[j], s1 = esrc[j + 1], s2 = esrc[j + 2], s3 = esrc[j + 3];
        float v0 = hs2[(size_t)s0 * C_OUT + c];
        float v1 = hs2[(size_t)s1 * C_OUT + c];
        float v2 = hs2[(size_t)s2 * C_OUT + c];
        float v3 = hs2[(size_t)s3 * C_OUT + c];
        acc += (v0 + v1) + (v2 + v3);
    }
    for (; j < end; ++j) acc += hs2[(size_t)esrc[j] * C_OUT + c];
    out[(size_t)node * C_OUT + c] = fmaf(dinv[node], acc, b2[c]);
}

extern "C" void kernel_launch(void* const* d_in, const int* in_sizes, int n_in,
                              void* d_out, int out_size, void* d_ws, size_t ws_size,
                              hipStream_t stream) {
    const float* x  = (const float*)d_in[0];
    const unsigned int* ei = (const unsigned int*)d_in[1];
    const float* W1 = (const float*)d_in[2];
    const float* b1 = (const float*)d_in[3];
    const float* W2 = (const float*)d_in[4];
    const float* b2 = (const float*)d_in[5];
    float* out = (float*)d_out;

    char* ws = (char*)d_ws;
    size_t off = 0;
    auto take = [&](size_t bytes) {
        char* p = ws + off;
        off += (bytes + 255) & ~(size_t)255;
        return p;
    };
    int*   flag     = (int*)  take(256);
    int*   esrc     = (int*)  take((size_t)N_EDGES * 4);
    int*   deg      = (int*)  take((size_t)N_NODES * 4);
    int*   rowstart = (int*)  take((size_t)(N_NODES + 1) * 4);
    int*   cursor   = (int*)  take((size_t)N_NODES * 4);
    int*   blksum   = (int*)  take((size_t)NB1 * 4);
    int*   blkoff   = (int*)  take((size_t)NB1 * 4);
    float* dinv     = (float*)take((size_t)N_NODES * 4);
    float* hs1      = (float*)take((size_t)N_NODES * C_HID * 4);
    float* y1       = (float*)take((size_t)N_NODES * C_HID * 4);
    float* hs2      = (float*)take((size_t)N_NODES * C_OUT * 4);

    // Degree histogram straight from edge_index
    k_detect<<<1, 64, 0, stream>>>(ei, flag);
    hipMemsetAsync(deg, 0, (size_t)N_NODES * 4, stream);
    k_hist<<<(N_EDGES + 255) / 256, 256, 0, stream>>>(ei, flag, deg);

    // CSR build: scan degrees, scatter src by dst
    k_scan1<<<NB1, 256, 0, stream>>>(deg, rowstart, blksum, dinv);
    k_scan2<<<1, 512, 0, stream>>>(blksum, blkoff);
    k_scan3<<<NB1, 256, 0, stream>>>(rowstart, blkoff, cursor);
    k_fill<<<(N_EDGES + 255) / 256, 256, 0, stream>>>(ei, flag, cursor, esrc);

    // Layer 1
    k_gemm1<<<NTILE, 256, 0, stream>>>(x, W1, dinv, hs1);
    k_agg1<<<N_NODES / 4, 256, 0, stream>>>(rowstart, esrc, hs1, dinv, b1, y1);

    // Layer 2
    k_gemm2<<<NTILE, 256, 0, stream>>>(y1, W2, dinv, hs2);
    k_agg2<<<N_NODES / 8, 256, 0, stream>>>(rowstart, esrc, hs2, dinv, b2, out);
}

// Round 4
// 391.072 us; speedup vs baseline: 1.6140x; 1.1046x over previous
//
#include <hip/hip_runtime.h>

#define N_NODES 100000
#define N_EDGES 1000000
#define C_IN 128
#define C_HID 64
#define C_OUT 32
#define NB1 ((N_NODES + 255) / 256)   // 391 scan blocks
#define G1_BLOCKS ((N_NODES + 63) / 64)  // 64 rows per block

// ---------------------------------------------------------------------------
// Edge-index dtype detection (int64 vs int32 storage).
// ---------------------------------------------------------------------------
__global__ __launch_bounds__(64) void k_detect(const unsigned int* __restrict__ ei,
                                               int* __restrict__ flag) {
    if (threadIdx.x == 0 && blockIdx.x == 0) {
        int is64 = 1;
        for (int i = 0; i < 64; ++i)
            if (ei[2 * i + 1] != 0u) { is64 = 0; break; }
        *flag = is64;
    }
}

// Histogram dst degrees straight from edge_index (no staging arrays).
__global__ __launch_bounds__(256) void k_hist(const unsigned int* __restrict__ ei,
                                              const int* __restrict__ flag,
                                              int* __restrict__ deg) {
    int e = blockIdx.x * 256 + threadIdx.x;
    if (e >= N_EDGES) return;
    int d;
    if (*flag) {  // int64: element i = 8B; take low dword via coalesced int2
        d = ((const int2*)ei)[(size_t)N_EDGES + e].x;
    } else {
        d = (int)ei[(size_t)N_EDGES + e];
    }
    atomicAdd(&deg[d], 1);
}

// ---------------------------------------------------------------------------
// 3-kernel exclusive prefix scan of deg -> rowstart; also dinv = rsqrt(deg+1).
// ---------------------------------------------------------------------------
__global__ __launch_bounds__(256) void k_scan1(const int* __restrict__ deg,
                                               int* __restrict__ rowstart,
                                               int* __restrict__ blksum,
                                               float* __restrict__ dinv) {
    __shared__ int sm[256];
    int i = blockIdx.x * 256 + threadIdx.x;
    int v = (i < N_NODES) ? deg[i] : 0;
    if (i < N_NODES) dinv[i] = rsqrtf((float)v + 1.0f);
    sm[threadIdx.x] = v;
    __syncthreads();
    for (int o = 1; o < 256; o <<= 1) {
        int t = (threadIdx.x >= o) ? sm[threadIdx.x - o] : 0;
        __syncthreads();
        sm[threadIdx.x] += t;
        __syncthreads();
    }
    if (i < N_NODES) rowstart[i] = sm[threadIdx.x] - v;   // exclusive, block-local
    if (threadIdx.x == 255) blksum[blockIdx.x] = sm[255];
}

__global__ __launch_bounds__(512) void k_scan2(const int* __restrict__ blksum,
                                               int* __restrict__ blkoff) {
    __shared__ int sm[512];
    int v = (threadIdx.x < NB1) ? blksum[threadIdx.x] : 0;
    sm[threadIdx.x] = v;
    __syncthreads();
    for (int o = 1; o < 512; o <<= 1) {
        int t = (threadIdx.x >= o) ? sm[threadIdx.x - o] : 0;
        __syncthreads();
        sm[threadIdx.x] += t;
        __syncthreads();
    }
    if (threadIdx.x < NB1) blkoff[threadIdx.x] = sm[threadIdx.x] - v;  // exclusive
}

__global__ __launch_bounds__(256) void k_scan3(int* __restrict__ rowstart,
                                               const int* __restrict__ blkoff,
                                               int* __restrict__ cursor) {
    int i = blockIdx.x * 256 + threadIdx.x;
    if (i < N_NODES) {
        int r = rowstart[i] + blkoff[i >> 8];
        rowstart[i] = r;
        cursor[i] = r;
    }
    if (i == 0) rowstart[N_NODES] = N_EDGES;
}

// Counting-sort scatter: esrc[] = src sorted by dst. Reads ei directly.
__global__ __launch_bounds__(256) void k_fill(const unsigned int* __restrict__ ei,
                                              const int* __restrict__ flag,
                                              int* __restrict__ cursor,
                                              int* __restrict__ esrc) {
    int e = blockIdx.x * 256 + threadIdx.x;
    if (e >= N_EDGES) return;
    int s, d;
    if (*flag) {
        s = ((const int2*)ei)[e].x;
        d = ((const int2*)ei)[(size_t)N_EDGES + e].x;
    } else {
        s = (int)ei[e];
        d = (int)ei[(size_t)N_EDGES + e];
    }
    int p = atomicAdd(&cursor[d], 1);
    esrc[p] = s;
}

// ---------------------------------------------------------------------------
// GEMM1: hs1[n][c] = (x[n][:] @ W1)[c] * dinv[n]    (128 -> 64)
// R3 post-mortem: wave-uniform x addresses were SCALARIZED (s_load streaming
// through the scalar cache = the 117 us). Fix: lane-dependent addresses.
//   wave = 2 half-waves x 8 rows; lane&31 owns channel pair (2c, 2c+1).
//   Per k4: 8 vector b128 x-loads (half-wave broadcast) + 4 ds_read_b64 w
//   + 64 FMAs into 16 accumulators. Block = 4 waves = 64 rows.
// ---------------------------------------------------------------------------
__global__ __launch_bounds__(256) void k_gemm1(const float* __restrict__ x,
                                               const float* __restrict__ W1,
                                               const float* __restrict__ dinv,
                                               float* __restrict__ hs1) {
    __shared__ float w[C_IN * C_HID];   // 32 KB, W1 row-major as-is
    for (int i = threadIdx.x; i < C_IN * C_HID; i += 256) w[i] = W1[i];
    __syncthreads();
    const int c2 = threadIdx.x & 31;          // channel pair index
    const int h  = (threadIdx.x >> 5) & 1;    // half-wave -> row group
    const int wid = threadIdx.x >> 6;
    const int row0 = blockIdx.x * 64 + wid * 16 + h * 8;
    const float4* x4 = reinterpret_cast<const float4*>(x);

    float acc0[8] = {0, 0, 0, 0, 0, 0, 0, 0};
    float acc1[8] = {0, 0, 0, 0, 0, 0, 0, 0};
#pragma unroll 2
    for (int k4 = 0; k4 < C_IN / 4; ++k4) {
        float4 xv[8];
#pragma unroll
        for (int r = 0; r < 8; ++r) {
            int rr = row0 + r; if (rr >= N_NODES) rr = N_NODES - 1;  // tail clamp
            xv[r] = x4[(size_t)rr * (C_IN / 4) + k4];   // vector load (lane-dep addr)
        }
        float2 wv[4];
#pragma unroll
        for (int j = 0; j < 4; ++j)
            wv[j] = *reinterpret_cast<const float2*>(&w[(k4 * 4 + j) * C_HID + 2 * c2]);
#pragma unroll
        for (int r = 0; r < 8; ++r) {
            acc0[r] = fmaf(xv[r].x, wv[0].x, acc0[r]);
            acc1[r] = fmaf(xv[r].x, wv[0].y, acc1[r]);
            acc0[r] = fmaf(xv[r].y, wv[1].x, acc0[r]);
            acc1[r] = fmaf(xv[r].y, wv[1].y, acc1[r]);
            acc0[r] = fmaf(xv[r].z, wv[2].x, acc0[r]);
            acc1[r] = fmaf(xv[r].z, wv[2].y, acc1[r]);
            acc0[r] = fmaf(xv[r].w, wv[3].x, acc0[r]);
            acc1[r] = fmaf(xv[r].w, wv[3].y, acc1[r]);
        }
    }
#pragma unroll
    for (int r = 0; r < 8; ++r) {
        int rr = row0 + r;
        if (rr < N_NODES) {
            float dv = dinv[rr];
            float2 o; o.x = acc0[r] * dv; o.y = acc1[r] * dv;
            *reinterpret_cast<float2*>(&hs1[(size_t)rr * C_HID + 2 * c2]) = o;
        }
    }
}

// ---------------------------------------------------------------------------
// Agg1 (+fused epilogue): y1[n] = relu(dinv[n]*(Σ_in hs1[src] + hs1[n]) + b1)
// One wave per node; lane = channel (64). 4-edge unroll for load ILP.
// ---------------------------------------------------------------------------
__global__ __launch_bounds__(256) void k_agg1(const int* __restrict__ rowstart,
                                              const int* __restrict__ esrc,
                                              const float* __restrict__ hs1,
                                              const float* __restrict__ dinv,
                                              const float* __restrict__ b1,
                                              float* __restrict__ y1) {
    int node = blockIdx.x * 4 + (threadIdx.x >> 6);
    int c = threadIdx.x & 63;
    int beg = rowstart[node], end = rowstart[node + 1];
    float acc = hs1[(size_t)node * C_HID + c];   // self-loop term
    int j = beg;
    for (; j + 3 < end; j += 4) {
        int s0 = esrc[j], s1 = esrc[j + 1], s2 = esrc[j + 2], s3 = esrc[j + 3];
        float v0 = hs1[(size_t)s0 * C_HID + c];
        float v1 = hs1[(size_t)s1 * C_HID + c];
        float v2 = hs1[(size_t)s2 * C_HID + c];
        float v3 = hs1[(size_t)s3 * C_HID + c];
        acc += (v0 + v1) + (v2 + v3);
    }
    for (; j < end; ++j) acc += hs1[(size_t)esrc[j] * C_HID + c];
    y1[(size_t)node * C_HID + c] = fmaxf(fmaf(dinv[node], acc, b1[c]), 0.f);
}

// ---------------------------------------------------------------------------
// GEMM2: hs2[n][c] = (y1[n][:] @ W2)[c] * dinv[n]    (64 -> 32)
// Lane-dependent addresses already (h splits rows) -> vector loads; 4 acc.
// ---------------------------------------------------------------------------
__global__ __launch_bounds__(256) void k_gemm2(const float* __restrict__ y1,
                                               const float* __restrict__ W2,
                                               const float* __restrict__ dinv,
                                               float* __restrict__ hs2) {
    __shared__ float w[C_HID * C_OUT];
    for (int i = threadIdx.x; i < C_HID * C_OUT; i += 256) w[i] = W2[i];
    __syncthreads();
    const int c = threadIdx.x & 31;
    const int h = (threadIdx.x >> 5) & 1;    // which half of the wave
    const int wid = threadIdx.x >> 6;
    const int row0 = blockIdx.x * 32 + wid * 8 + h * 4;
    const float4* y4 = reinterpret_cast<const float4*>(y1);
    float acc[4] = {0.f, 0.f, 0.f, 0.f};
    for (int k4 = 0; k4 < C_HID / 4; ++k4) {
        float4 yv[4];
#pragma unroll
        for (int r = 0; r < 4; ++r)
            yv[r] = y4[(size_t)(row0 + r) * (C_HID / 4) + k4];
        float w0 = w[(k4 * 4 + 0) * C_OUT + c];
        float w1 = w[(k4 * 4 + 1) * C_OUT + c];
        float w2 = w[(k4 * 4 + 2) * C_OUT + c];
        float w3 = w[(k4 * 4 + 3) * C_OUT + c];
#pragma unroll
        for (int r = 0; r < 4; ++r) {
            acc[r] = fmaf(yv[r].x, w0, acc[r]);
            acc[r] = fmaf(yv[r].y, w1, acc[r]);
            acc[r] = fmaf(yv[r].z, w2, acc[r]);
            acc[r] = fmaf(yv[r].w, w3, acc[r]);
        }
    }
#pragma unroll
    for (int r = 0; r < 4; ++r)
        hs2[(size_t)(row0 + r) * C_OUT + c] = acc[r] * dinv[row0 + r];
}

// Agg2 (+fused epilogue, no relu): out = dinv*(Σ hs2[src] + hs2[n]) + b2
__global__ __launch_bounds__(256) void k_agg2(const int* __restrict__ rowstart,
                                              const int* __restrict__ esrc,
                                              const float* __restrict__ hs2,
                                              const float* __restrict__ dinv,
                                              const float* __restrict__ b2,
                                              float* __restrict__ out) {
    int node = blockIdx.x * 8 + (threadIdx.x >> 5);
    int c = threadIdx.x & 31;
    int beg = rowstart[node], end = rowstart[node + 1];
    float acc = hs2[(size_t)node * C_OUT + c];
    int j = beg;
    for (; j + 3 < end; j += 4) {
        int s0 = esrc[j], s1 = esrc[j + 1], s2 = esrc[j + 2], s3 = esrc[j + 3];
        float v0 = hs2[(size_t)s0 * C_OUT + c];
        float v1 = hs2[(size_t)s1 * C_OUT + c];
        float v2 = hs2[(size_t)s2 * C_OUT + c];
        float v3 = hs2[(size_t)s3 * C_OUT + c];
        acc += (v0 + v1) + (v2 + v3);
    }
    for (; j < end; ++j) acc += hs2[(size_t)esrc[j] * C_OUT + c];
    out[(size_t)node * C_OUT + c] = fmaf(dinv[node], acc, b2[c]);
}

extern "C" void kernel_launch(void* const* d_in, const int* in_sizes, int n_in,
                              void* d_out, int out_size, void* d_ws, size_t ws_size,
                              hipStream_t stream) {
    const float* x  = (const float*)d_in[0];
    const unsigned int* ei = (const unsigned int*)d_in[1];
    const float* W1 = (const float*)d_in[2];
    const float* b1 = (const float*)d_in[3];
    const float* W2 = (const float*)d_in[4];
    const float* b2 = (const float*)d_in[5];
    float* out = (float*)d_out;

    char* ws = (char*)d_ws;
    size_t off = 0;
    auto take = [&](size_t bytes) {
        char* p = ws + off;
        off += (bytes + 255) & ~(size_t)255;
        return p;
    };
    int*   flag     = (int*)  take(256);
    int*   esrc     = (int*)  take((size_t)N_EDGES * 4);
    int*   deg      = (int*)  take((size_t)N_NODES * 4);
    int*   rowstart = (int*)  take((size_t)(N_NODES + 1) * 4);
    int*   cursor   = (int*)  take((size_t)N_NODES * 4);
    int*   blksum   = (int*)  take((size_t)NB1 * 4);
    int*   blkoff   = (int*)  take((size_t)NB1 * 4);
    float* dinv     = (float*)take((size_t)N_NODES * 4);
    float* hs1      = (float*)take((size_t)N_NODES * C_HID * 4);
    float* y1       = (float*)take((size_t)N_NODES * C_HID * 4);
    float* hs2      = (float*)take((size_t)N_NODES * C_OUT * 4);

    // Degree histogram straight from edge_index
    k_detect<<<1, 64, 0, stream>>>(ei, flag);
    hipMemsetAsync(deg, 0, (size_t)N_NODES * 4, stream);
    k_hist<<<(N_EDGES + 255) / 256, 256, 0, stream>>>(ei, flag, deg);

    // CSR build: scan degrees, scatter src by dst
    k_scan1<<<NB1, 256, 0, stream>>>(deg, rowstart, blksum, dinv);
    k_scan2<<<1, 512, 0, stream>>>(blksum, blkoff);
    k_scan3<<<NB1, 256, 0, stream>>>(rowstart, blkoff, cursor);
    k_fill<<<(N_EDGES + 255) / 256, 256, 0, stream>>>(ei, flag, cursor, esrc);

    // Layer 1
    k_gemm1<<<G1_BLOCKS, 256, 0, stream>>>(x, W1, dinv, hs1);
    k_agg1<<<N_NODES / 4, 256, 0, stream>>>(rowstart, esrc, hs1, dinv, b1, y1);

    // Layer 2
    k_gemm2<<<N_NODES / 32, 256, 0, stream>>>(y1, W2, dinv, hs2);
    k_agg2<<<N_NODES / 8, 256, 0, stream>>>(rowstart, esrc, hs2, dinv, b2, out);
}

// Round 5
// 353.256 us; speedup vs baseline: 1.7867x; 1.1070x over previous
//
#include <hip/hip_runtime.h>

#define N_NODES 100000
#define N_EDGES 1000000
#define C_IN 128
#define C_HID 64
#define C_OUT 32
#define NB1 ((N_NODES + 255) / 256)      // 391 scan blocks
#define G1_BLOCKS ((N_NODES + 63) / 64)  // 64 rows per block

// ---------------------------------------------------------------------------
// Edge-index dtype detection (int64 vs int32 storage).
// ---------------------------------------------------------------------------
__global__ __launch_bounds__(64) void k_detect(const unsigned int* __restrict__ ei,
                                               int* __restrict__ flag) {
    if (threadIdx.x == 0 && blockIdx.x == 0) {
        int is64 = 1;
        for (int i = 0; i < 64; ++i)
            if (ei[2 * i + 1] != 0u) { is64 = 0; break; }
        *flag = is64;
    }
}

// ---------------------------------------------------------------------------
// Rank pass: ONE atomic pass builds the degree histogram AND per-edge rank
// (position within its dst's bucket). rank written coalesced + non-temporal.
// 4 independent edges per thread (grid-stride groups) for atomic-latency MLP.
// ---------------------------------------------------------------------------
__global__ __launch_bounds__(256) void k_rank(const unsigned int* __restrict__ ei,
                                              const int* __restrict__ flag,
                                              int* __restrict__ deg,
                                              int* __restrict__ rank) {
    const int T = gridDim.x * 256;
    const int t = blockIdx.x * 256 + threadIdx.x;
    const bool is64 = (*flag != 0);
    int d[4];
#pragma unroll
    for (int i = 0; i < 4; ++i) {
        int e = t + i * T;
        if (e < N_EDGES)
            d[i] = is64 ? ((const int2*)ei)[(size_t)N_EDGES + e].x
                        : (int)ei[(size_t)N_EDGES + e];
    }
    int r[4];
#pragma unroll
    for (int i = 0; i < 4; ++i) {
        int e = t + i * T;
        if (e < N_EDGES) r[i] = atomicAdd(&deg[d[i]], 1);
    }
#pragma unroll
    for (int i = 0; i < 4; ++i) {
        int e = t + i * T;
        if (e < N_EDGES) __builtin_nontemporal_store(r[i], &rank[e]);
    }
}

// ---------------------------------------------------------------------------
// 3-kernel exclusive prefix scan of deg -> rowstart; also dinv = rsqrt(deg+1).
// ---------------------------------------------------------------------------
__global__ __launch_bounds__(256) void k_scan1(const int* __restrict__ deg,
                                               int* __restrict__ rowstart,
                                               int* __restrict__ blksum,
                                               float* __restrict__ dinv) {
    __shared__ int sm[256];
    int i = blockIdx.x * 256 + threadIdx.x;
    int v = (i < N_NODES) ? deg[i] : 0;
    if (i < N_NODES) dinv[i] = rsqrtf((float)v + 1.0f);
    sm[threadIdx.x] = v;
    __syncthreads();
    for (int o = 1; o < 256; o <<= 1) {
        int t = (threadIdx.x >= o) ? sm[threadIdx.x - o] : 0;
        __syncthreads();
        sm[threadIdx.x] += t;
        __syncthreads();
    }
    if (i < N_NODES) rowstart[i] = sm[threadIdx.x] - v;   // exclusive, block-local
    if (threadIdx.x == 255) blksum[blockIdx.x] = sm[255];
}

__global__ __launch_bounds__(512) void k_scan2(const int* __restrict__ blksum,
                                               int* __restrict__ blkoff) {
    __shared__ int sm[512];
    int v = (threadIdx.x < NB1) ? blksum[threadIdx.x] : 0;
    sm[threadIdx.x] = v;
    __syncthreads();
    for (int o = 1; o < 512; o <<= 1) {
        int t = (threadIdx.x >= o) ? sm[threadIdx.x - o] : 0;
        __syncthreads();
        sm[threadIdx.x] += t;
        __syncthreads();
    }
    if (threadIdx.x < NB1) blkoff[threadIdx.x] = sm[threadIdx.x] - v;  // exclusive
}

__global__ __launch_bounds__(256) void k_scan3(int* __restrict__ rowstart,
                                               const int* __restrict__ blkoff) {
    int i = blockIdx.x * 256 + threadIdx.x;
    if (i < N_NODES) rowstart[i] += blkoff[i >> 8];
    if (i == 0) rowstart[N_NODES] = N_EDGES;
}

// ---------------------------------------------------------------------------
// Fill pass: p = rowstart[dst] + rank[e]; esrc[p] = src. NO atomics.
// Non-temporal scatter store: bypass L2 so the 1M partial-line evictions
// (R4: 70 MB WRITE_SIZE for a 4 MB array) disappear.
// ---------------------------------------------------------------------------
__global__ __launch_bounds__(256) void k_fill2(const unsigned int* __restrict__ ei,
                                               const int* __restrict__ flag,
                                               const int* __restrict__ rowstart,
                                               const int* __restrict__ rank,
                                               int* __restrict__ esrc) {
    const int T = gridDim.x * 256;
    const int t = blockIdx.x * 256 + threadIdx.x;
    const bool is64 = (*flag != 0);
#pragma unroll
    for (int i = 0; i < 4; ++i) {
        int e = t + i * T;
        if (e < N_EDGES) {
            int s, d;
            if (is64) {
                s = ((const int2*)ei)[e].x;
                d = ((const int2*)ei)[(size_t)N_EDGES + e].x;
            } else {
                s = (int)ei[e];
                d = (int)ei[(size_t)N_EDGES + e];
            }
            int p = rowstart[d] + rank[e];
            __builtin_nontemporal_store(s, &esrc[p]);
        }
    }
}

// ---------------------------------------------------------------------------
// GEMM1: hs1[n][c] = (x[n][:] @ W1)[c] * dinv[n]    (128 -> 64)
// Lane-dependent x addresses (half-wave row split) keep loads on the vector
// path (R3: uniform addresses were scalarized -> scalar-cache-bound).
// ---------------------------------------------------------------------------
__global__ __launch_bounds__(256) void k_gemm1(const float* __restrict__ x,
                                               const float* __restrict__ W1,
                                               const float* __restrict__ dinv,
                                               float* __restrict__ hs1) {
    __shared__ float w[C_IN * C_HID];   // 32 KB, W1 row-major as-is
    for (int i = threadIdx.x; i < C_IN * C_HID; i += 256) w[i] = W1[i];
    __syncthreads();
    const int c2 = threadIdx.x & 31;          // channel pair index
    const int h  = (threadIdx.x >> 5) & 1;    // half-wave -> row group
    const int wid = threadIdx.x >> 6;
    const int row0 = blockIdx.x * 64 + wid * 16 + h * 8;
    const float4* x4 = reinterpret_cast<const float4*>(x);

    float acc0[8] = {0, 0, 0, 0, 0, 0, 0, 0};
    float acc1[8] = {0, 0, 0, 0, 0, 0, 0, 0};
#pragma unroll 2
    for (int k4 = 0; k4 < C_IN / 4; ++k4) {
        float4 xv[8];
#pragma unroll
        for (int r = 0; r < 8; ++r) {
            int rr = row0 + r; if (rr >= N_NODES) rr = N_NODES - 1;  // tail clamp
            xv[r] = x4[(size_t)rr * (C_IN / 4) + k4];   // vector load (lane-dep addr)
        }
        float2 wv[4];
#pragma unroll
        for (int j = 0; j < 4; ++j)
            wv[j] = *reinterpret_cast<const float2*>(&w[(k4 * 4 + j) * C_HID + 2 * c2]);
#pragma unroll
        for (int r = 0; r < 8; ++r) {
            acc0[r] = fmaf(xv[r].x, wv[0].x, acc0[r]);
            acc1[r] = fmaf(xv[r].x, wv[0].y, acc1[r]);
            acc0[r] = fmaf(xv[r].y, wv[1].x, acc0[r]);
            acc1[r] = fmaf(xv[r].y, wv[1].y, acc1[r]);
            acc0[r] = fmaf(xv[r].z, wv[2].x, acc0[r]);
            acc1[r] = fmaf(xv[r].z, wv[2].y, acc1[r]);
            acc0[r] = fmaf(xv[r].w, wv[3].x, acc0[r]);
            acc1[r] = fmaf(xv[r].w, wv[3].y, acc1[r]);
        }
    }
#pragma unroll
    for (int r = 0; r < 8; ++r) {
        int rr = row0 + r;
        if (rr < N_NODES) {
            float dv = dinv[rr];
            float2 o; o.x = acc0[r] * dv; o.y = acc1[r] * dv;
            *reinterpret_cast<float2*>(&hs1[(size_t)rr * C_HID + 2 * c2]) = o;
        }
    }
}

// ---------------------------------------------------------------------------
// Agg1 (+fused epilogue): y1[n] = relu(dinv[n]*(Σ_in hs1[src] + hs1[n]) + b1)
// One wave per node; lane = channel (64). 4-edge unroll for load ILP.
// ---------------------------------------------------------------------------
__global__ __launch_bounds__(256) void k_agg1(const int* __restrict__ rowstart,
                                              const int* __restrict__ esrc,
                                              const float* __restrict__ hs1,
                                              const float* __restrict__ dinv,
                                              const float* __restrict__ b1,
                                              float* __restrict__ y1) {
    int node = blockIdx.x * 4 + (threadIdx.x >> 6);
    int c = threadIdx.x & 63;
    int beg = rowstart[node], end = rowstart[node + 1];
    float acc = hs1[(size_t)node * C_HID + c];   // self-loop term
    int j = beg;
    for (; j + 3 < end; j += 4) {
        int s0 = esrc[j], s1 = esrc[j + 1], s2 = esrc[j + 2], s3 = esrc[j + 3];
        float v0 = hs1[(size_t)s0 * C_HID + c];
        float v1 = hs1[(size_t)s1 * C_HID + c];
        float v2 = hs1[(size_t)s2 * C_HID + c];
        float v3 = hs1[(size_t)s3 * C_HID + c];
        acc += (v0 + v1) + (v2 + v3);
    }
    for (; j < end; ++j) acc += hs1[(size_t)esrc[j] * C_HID + c];
    y1[(size_t)node * C_HID + c] = fmaxf(fmaf(dinv[node], acc, b1[c]), 0.f);
}

// ---------------------------------------------------------------------------
// GEMM2: hs2[n][c] = (y1[n][:] @ W2)[c] * dinv[n]    (64 -> 32)
// ---------------------------------------------------------------------------
__global__ __launch_bounds__(256) void k_gemm2(const float* __restrict__ y1,
                                               const float* __restrict__ W2,
                                               const float* __restrict__ dinv,
                                               float* __restrict__ hs2) {
    __shared__ float w[C_HID * C_OUT];
    for (int i = threadIdx.x; i < C_HID * C_OUT; i += 256) w[i] = W2[i];
    __syncthreads();
    const int c = threadIdx.x & 31;
    const int h = (threadIdx.x >> 5) & 1;    // which half of the wave
    const int wid = threadIdx.x >> 6;
    const int row0 = blockIdx.x * 32 + wid * 8 + h * 4;
    const float4* y4 = reinterpret_cast<const float4*>(y1);
    float acc[4] = {0.f, 0.f, 0.f, 0.f};
    for (int k4 = 0; k4 < C_HID / 4; ++k4) {
        float4 yv[4];
#pragma unroll
        for (int r = 0; r < 4; ++r)
            yv[r] = y4[(size_t)(row0 + r) * (C_HID / 4) + k4];
        float w0 = w[(k4 * 4 + 0) * C_OUT + c];
        float w1 = w[(k4 * 4 + 1) * C_OUT + c];
        float w2 = w[(k4 * 4 + 2) * C_OUT + c];
        float w3 = w[(k4 * 4 + 3) * C_OUT + c];
#pragma unroll
        for (int r = 0; r < 4; ++r) {
            acc[r] = fmaf(yv[r].x, w0, acc[r]);
            acc[r] = fmaf(yv[r].y, w1, acc[r]);
            acc[r] = fmaf(yv[r].z, w2, acc[r]);
            acc[r] = fmaf(yv[r].w, w3, acc[r]);
        }
    }
#pragma unroll
    for (int r = 0; r < 4; ++r)
        hs2[(size_t)(row0 + r) * C_OUT + c] = acc[r] * dinv[row0 + r];
}

// Agg2 (+fused epilogue, no relu): out = dinv*(Σ hs2[src] + hs2[n]) + b2
__global__ __launch_bounds__(256) void k_agg2(const int* __restrict__ rowstart,
                                              const int* __restrict__ esrc,
                                              const float* __restrict__ hs2,
                                              const float* __restrict__ dinv,
                                              const float* __restrict__ b2,
                                              float* __restrict__ out) {
    int node = blockIdx.x * 8 + (threadIdx.x >> 5);
    int c = threadIdx.x & 31;
    int beg = rowstart[node], end = rowstart[node + 1];
    float acc = hs2[(size_t)node * C_OUT + c];
    int j = beg;
    for (; j + 3 < end; j += 4) {
        int s0 = esrc[j], s1 = esrc[j + 1], s2 = esrc[j + 2], s3 = esrc[j + 3];
        float v0 = hs2[(size_t)s0 * C_OUT + c];
        float v1 = hs2[(size_t)s1 * C_OUT + c];
        float v2 = hs2[(size_t)s2 * C_OUT + c];
        float v3 = hs2[(size_t)s3 * C_OUT + c];
        acc += (v0 + v1) + (v2 + v3);
    }
    for (; j < end; ++j) acc += hs2[(size_t)esrc[j] * C_OUT + c];
    out[(size_t)node * C_OUT + c] = fmaf(dinv[node], acc, b2[c]);
}

extern "C" void kernel_launch(void* const* d_in, const int* in_sizes, int n_in,
                              void* d_out, int out_size, void* d_ws, size_t ws_size,
                              hipStream_t stream) {
    const float* x  = (const float*)d_in[0];
    const unsigned int* ei = (const unsigned int*)d_in[1];
    const float* W1 = (const float*)d_in[2];
    const float* b1 = (const float*)d_in[3];
    const float* W2 = (const float*)d_in[4];
    const float* b2 = (const float*)d_in[5];
    float* out = (float*)d_out;

    char* ws = (char*)d_ws;
    size_t off = 0;
    auto take = [&](size_t bytes) {
        char* p = ws + off;
        off += (bytes + 255) & ~(size_t)255;
        return p;
    };
    int*   flag     = (int*)  take(256);
    int*   esrc     = (int*)  take((size_t)N_EDGES * 4);
    int*   rank     = (int*)  take((size_t)N_EDGES * 4);
    int*   deg      = (int*)  take((size_t)N_NODES * 4);
    int*   rowstart = (int*)  take((size_t)(N_NODES + 1) * 4);
    int*   blksum   = (int*)  take((size_t)NB1 * 4);
    int*   blkoff   = (int*)  take((size_t)NB1 * 4);
    float* dinv     = (float*)take((size_t)N_NODES * 4);
    float* hs1      = (float*)take((size_t)N_NODES * C_HID * 4);
    float* y1       = (float*)take((size_t)N_NODES * C_HID * 4);
    float* hs2      = (float*)take((size_t)N_NODES * C_OUT * 4);

    // Rank pass: degree histogram + per-edge rank in one atomic sweep
    k_detect<<<1, 64, 0, stream>>>(ei, flag);
    hipMemsetAsync(deg, 0, (size_t)N_NODES * 4, stream);
    k_rank<<<1024, 256, 0, stream>>>(ei, flag, deg, rank);

    // CSR offsets: scan degrees (+ dinv)
    k_scan1<<<NB1, 256, 0, stream>>>(deg, rowstart, blksum, dinv);
    k_scan2<<<1, 512, 0, stream>>>(blksum, blkoff);
    k_scan3<<<NB1, 256, 0, stream>>>(rowstart, blkoff);

    // Atomic-free fill with non-temporal scatter stores
    k_fill2<<<1024, 256, 0, stream>>>(ei, flag, rowstart, rank, esrc);

    // Layer 1
    k_gemm1<<<G1_BLOCKS, 256, 0, stream>>>(x, W1, dinv, hs1);
    k_agg1<<<N_NODES / 4, 256, 0, stream>>>(rowstart, esrc, hs1, dinv, b1, y1);

    // Layer 2
    k_gemm2<<<N_NODES / 32, 256, 0, stream>>>(y1, W2, dinv, hs2);
    k_agg2<<<N_NODES / 8, 256, 0, stream>>>(rowstart, esrc, hs2, dinv, b2, out);
}

// Round 6
// 311.071 us; speedup vs baseline: 2.0290x; 1.1356x over previous
//
#include <hip/hip_runtime.h>

#define N_NODES 100000
#define N_EDGES 1000000
#define C_IN 128
#define C_HID 64
#define C_OUT 32
#define NB1 ((N_NODES + 255) / 256)      // 391 scan blocks
#define GT_BLOCKS ((N_NODES + 63) / 64)  // 1563 tiles of 64 rows

// ---------------------------------------------------------------------------
// Edge-index dtype detection (int64 vs int32 storage).
// ---------------------------------------------------------------------------
__global__ __launch_bounds__(64) void k_detect(const unsigned int* __restrict__ ei,
                                               int* __restrict__ flag) {
    if (threadIdx.x == 0 && blockIdx.x == 0) {
        int is64 = 1;
        for (int i = 0; i < 64; ++i)
            if (ei[2 * i + 1] != 0u) { is64 = 0; break; }
        *flag = is64;
    }
}

// ---------------------------------------------------------------------------
// Rank pass: ONE atomic pass builds the degree histogram AND per-edge rank.
// ---------------------------------------------------------------------------
__global__ __launch_bounds__(256) void k_rank(const unsigned int* __restrict__ ei,
                                              const int* __restrict__ flag,
                                              int* __restrict__ deg,
                                              int* __restrict__ rank) {
    const int T = gridDim.x * 256;
    const int t = blockIdx.x * 256 + threadIdx.x;
    const bool is64 = (*flag != 0);
    int d[4];
#pragma unroll
    for (int i = 0; i < 4; ++i) {
        int e = t + i * T;
        if (e < N_EDGES)
            d[i] = is64 ? ((const int2*)ei)[(size_t)N_EDGES + e].x
                        : (int)ei[(size_t)N_EDGES + e];
    }
    int r[4];
#pragma unroll
    for (int i = 0; i < 4; ++i) {
        int e = t + i * T;
        if (e < N_EDGES) r[i] = atomicAdd(&deg[d[i]], 1);
    }
#pragma unroll
    for (int i = 0; i < 4; ++i) {
        int e = t + i * T;
        if (e < N_EDGES) __builtin_nontemporal_store(r[i], &rank[e]);
    }
}

// ---------------------------------------------------------------------------
// 3-kernel exclusive prefix scan of deg -> rowstart; also dinv = rsqrt(deg+1).
// ---------------------------------------------------------------------------
__global__ __launch_bounds__(256) void k_scan1(const int* __restrict__ deg,
                                               int* __restrict__ rowstart,
                                               int* __restrict__ blksum,
                                               float* __restrict__ dinv) {
    __shared__ int sm[256];
    int i = blockIdx.x * 256 + threadIdx.x;
    int v = (i < N_NODES) ? deg[i] : 0;
    if (i < N_NODES) dinv[i] = rsqrtf((float)v + 1.0f);
    sm[threadIdx.x] = v;
    __syncthreads();
    for (int o = 1; o < 256; o <<= 1) {
        int t = (threadIdx.x >= o) ? sm[threadIdx.x - o] : 0;
        __syncthreads();
        sm[threadIdx.x] += t;
        __syncthreads();
    }
    if (i < N_NODES) rowstart[i] = sm[threadIdx.x] - v;   // exclusive, block-local
    if (threadIdx.x == 255) blksum[blockIdx.x] = sm[255];
}

__global__ __launch_bounds__(512) void k_scan2(const int* __restrict__ blksum,
                                               int* __restrict__ blkoff) {
    __shared__ int sm[512];
    int v = (threadIdx.x < NB1) ? blksum[threadIdx.x] : 0;
    sm[threadIdx.x] = v;
    __syncthreads();
    for (int o = 1; o < 512; o <<= 1) {
        int t = (threadIdx.x >= o) ? sm[threadIdx.x - o] : 0;
        __syncthreads();
        sm[threadIdx.x] += t;
        __syncthreads();
    }
    if (threadIdx.x < NB1) blkoff[threadIdx.x] = sm[threadIdx.x] - v;  // exclusive
}

__global__ __launch_bounds__(256) void k_scan3(int* __restrict__ rowstart,
                                               const int* __restrict__ blkoff) {
    int i = blockIdx.x * 256 + threadIdx.x;
    if (i < N_NODES) rowstart[i] += blkoff[i >> 8];
    if (i == 0) rowstart[N_NODES] = N_EDGES;
}

// ---------------------------------------------------------------------------
// Fill pass: p = rowstart[dst] + rank[e]; esrc[p] = src. No atomics; NT store.
// ---------------------------------------------------------------------------
__global__ __launch_bounds__(256) void k_fill2(const unsigned int* __restrict__ ei,
                                               const int* __restrict__ flag,
                                               const int* __restrict__ rowstart,
                                               const int* __restrict__ rank,
                                               int* __restrict__ esrc) {
    const int T = gridDim.x * 256;
    const int t = blockIdx.x * 256 + threadIdx.x;
    const bool is64 = (*flag != 0);
#pragma unroll
    for (int i = 0; i < 4; ++i) {
        int e = t + i * T;
        if (e < N_EDGES) {
            int s, d;
            if (is64) {
                s = ((const int2*)ei)[e].x;
                d = ((const int2*)ei)[(size_t)N_EDGES + e].x;
            } else {
                s = (int)ei[e];
                d = (int)ei[(size_t)N_EDGES + e];
            }
            int p = rowstart[d] + rank[e];
            __builtin_nontemporal_store(s, &esrc[p]);
        }
    }
}

// ---------------------------------------------------------------------------
// GEMM1: hs1[n][c] = (x[n][:] @ W1)[c] * dinv[n]    (128 -> 64)
// R5 post-mortem: 16B broadcast GLOBAL loads (~500cy latency, 8 waves/CU)
// stalled FMAs at 22% VALUBusy. Fix: stage the 64-row x tile in LDS with
// fully-coalesced float4 loads (every lane distinct addr, 16 in flight),
// then FMA-loop reads are LDS broadcasts (~120cy, lgkmcnt-pipelined).
// LDS = 32KB W + 32KB xt -> 2 blocks/CU; block i+1 stages while i computes.
// ---------------------------------------------------------------------------
__global__ __launch_bounds__(256) void k_gemm1(const float* __restrict__ x,
                                               const float* __restrict__ W1,
                                               const float* __restrict__ dinv,
                                               float* __restrict__ hs1) {
    __shared__ float w[C_IN * C_HID];   // 32 KB
    __shared__ float xt[64 * C_IN];     // 32 KB
    const int t = threadIdx.x;
    {
        const float4* W4 = (const float4*)W1;
        const float4* x4g = (const float4*)x;
        float4* w4 = (float4*)w;
        float4* xt4w = (float4*)xt;
        const size_t base = (size_t)blockIdx.x * 64 * (C_IN / 4);
        const size_t xmax = (size_t)N_NODES * (C_IN / 4) - 1;
#pragma unroll
        for (int j = 0; j < 8; ++j) {
            size_t idx = base + t + j * 256;
            if (idx > xmax) idx = xmax;            // tail clamp (dup reads ok)
            xt4w[t + j * 256] = x4g[idx];
            w4[t + j * 256] = W4[t + j * 256];
        }
    }
    __syncthreads();
    const int c2 = t & 31;          // channel pair
    const int h  = (t >> 5) & 1;    // half-wave -> row group
    const int wid = t >> 6;
    const int lrow0 = wid * 16 + h * 8;
    const int grow0 = blockIdx.x * 64 + lrow0;
    const float4* xt4 = (const float4*)xt;

    float acc0[8] = {0, 0, 0, 0, 0, 0, 0, 0};
    float acc1[8] = {0, 0, 0, 0, 0, 0, 0, 0};
#pragma unroll 2
    for (int k4 = 0; k4 < C_IN / 4; ++k4) {
        float4 xv[8];
#pragma unroll
        for (int r = 0; r < 8; ++r)
            xv[r] = xt4[(lrow0 + r) * (C_IN / 4) + k4];   // LDS broadcast
        float2 wv[4];
#pragma unroll
        for (int j = 0; j < 4; ++j)
            wv[j] = *reinterpret_cast<const float2*>(&w[(k4 * 4 + j) * C_HID + 2 * c2]);
#pragma unroll
        for (int r = 0; r < 8; ++r) {
            acc0[r] = fmaf(xv[r].x, wv[0].x, acc0[r]);
            acc1[r] = fmaf(xv[r].x, wv[0].y, acc1[r]);
            acc0[r] = fmaf(xv[r].y, wv[1].x, acc0[r]);
            acc1[r] = fmaf(xv[r].y, wv[1].y, acc1[r]);
            acc0[r] = fmaf(xv[r].z, wv[2].x, acc0[r]);
            acc1[r] = fmaf(xv[r].z, wv[2].y, acc1[r]);
            acc0[r] = fmaf(xv[r].w, wv[3].x, acc0[r]);
            acc1[r] = fmaf(xv[r].w, wv[3].y, acc1[r]);
        }
    }
#pragma unroll
    for (int r = 0; r < 8; ++r) {
        int rr = grow0 + r;
        if (rr < N_NODES) {
            float dv = dinv[rr];
            float2 o; o.x = acc0[r] * dv; o.y = acc1[r] * dv;
            *reinterpret_cast<float2*>(&hs1[(size_t)rr * C_HID + 2 * c2]) = o;
        }
    }
}

// ---------------------------------------------------------------------------
// Agg1 (+fused epilogue): y1[n] = relu(dinv[n]*(Σ_in hs1[src] + hs1[n]) + b1)
// ---------------------------------------------------------------------------
__global__ __launch_bounds__(256) void k_agg1(const int* __restrict__ rowstart,
                                              const int* __restrict__ esrc,
                                              const float* __restrict__ hs1,
                                              const float* __restrict__ dinv,
                                              const float* __restrict__ b1,
                                              float* __restrict__ y1) {
    int node = blockIdx.x * 4 + (threadIdx.x >> 6);
    int c = threadIdx.x & 63;
    int beg = rowstart[node], end = rowstart[node + 1];
    float acc = hs1[(size_t)node * C_HID + c];   // self-loop term
    int j = beg;
    for (; j + 3 < end; j += 4) {
        int s0 = esrc[j], s1 = esrc[j + 1], s2 = esrc[j + 2], s3 = esrc[j + 3];
        float v0 = hs1[(size_t)s0 * C_HID + c];
        float v1 = hs1[(size_t)s1 * C_HID + c];
        float v2 = hs1[(size_t)s2 * C_HID + c];
        float v3 = hs1[(size_t)s3 * C_HID + c];
        acc += (v0 + v1) + (v2 + v3);
    }
    for (; j < end; ++j) acc += hs1[(size_t)esrc[j] * C_HID + c];
    y1[(size_t)node * C_HID + c] = fmaxf(fmaf(dinv[node], acc, b1[c]), 0.f);
}

// ---------------------------------------------------------------------------
// GEMM2: hs2[n][c] = (y1[n][:] @ W2)[c] * dinv[n]    (64 -> 32)
// Same LDS-staged structure: 8KB W2 + 16KB y tile = 24KB -> 6 blocks/CU.
// Wave = 2 half-waves x 8 rows x 32 ch; block = 64 rows.
// ---------------------------------------------------------------------------
__global__ __launch_bounds__(256) void k_gemm2(const float* __restrict__ y1,
                                               const float* __restrict__ W2,
                                               const float* __restrict__ dinv,
                                               float* __restrict__ hs2) {
    __shared__ float w[C_HID * C_OUT];   // 8 KB
    __shared__ float yt[64 * C_HID];     // 16 KB
    const int t = threadIdx.x;
    {
        const float4* W4 = (const float4*)W2;
        const float4* y4g = (const float4*)y1;
        float4* w4 = (float4*)w;
        float4* yt4w = (float4*)yt;
        const size_t base = (size_t)blockIdx.x * 64 * (C_HID / 4);
        const size_t ymax = (size_t)N_NODES * (C_HID / 4) - 1;
#pragma unroll
        for (int j = 0; j < 4; ++j) {
            size_t idx = base + t + j * 256;
            if (idx > ymax) idx = ymax;
            yt4w[t + j * 256] = y4g[idx];
        }
#pragma unroll
        for (int j = 0; j < 2; ++j)
            w4[t + j * 256] = W4[t + j * 256];
    }
    __syncthreads();
    const int c = t & 31;
    const int h = (t >> 5) & 1;
    const int wid = t >> 6;
    const int lrow0 = wid * 16 + h * 8;
    const int grow0 = blockIdx.x * 64 + lrow0;
    const float4* yt4 = (const float4*)yt;

    float acc[8] = {0, 0, 0, 0, 0, 0, 0, 0};
#pragma unroll 2
    for (int k4 = 0; k4 < C_HID / 4; ++k4) {
        float4 yv[8];
#pragma unroll
        for (int r = 0; r < 8; ++r)
            yv[r] = yt4[(lrow0 + r) * (C_HID / 4) + k4];
        float w0 = w[(k4 * 4 + 0) * C_OUT + c];
        float w1 = w[(k4 * 4 + 1) * C_OUT + c];
        float w2 = w[(k4 * 4 + 2) * C_OUT + c];
        float w3 = w[(k4 * 4 + 3) * C_OUT + c];
#pragma unroll
        for (int r = 0; r < 8; ++r) {
            acc[r] = fmaf(yv[r].x, w0, acc[r]);
            acc[r] = fmaf(yv[r].y, w1, acc[r]);
            acc[r] = fmaf(yv[r].z, w2, acc[r]);
            acc[r] = fmaf(yv[r].w, w3, acc[r]);
        }
    }
#pragma unroll
    for (int r = 0; r < 8; ++r) {
        int rr = grow0 + r;
        if (rr < N_NODES)
            hs2[(size_t)rr * C_OUT + c] = acc[r] * dinv[rr];
    }
}

// Agg2 (+fused epilogue, no relu): out = dinv*(Σ hs2[src] + hs2[n]) + b2
__global__ __launch_bounds__(256) void k_agg2(const int* __restrict__ rowstart,
                                              const int* __restrict__ esrc,
                                              const float* __restrict__ hs2,
                                              const float* __restrict__ dinv,
                                              const float* __restrict__ b2,
                                              float* __restrict__ out) {
    int node = blockIdx.x * 8 + (threadIdx.x >> 5);
    int c = threadIdx.x & 31;
    int beg = rowstart[node], end = rowstart[node + 1];
    float acc = hs2[(size_t)node * C_OUT + c];
    int j = beg;
    for (; j + 3 < end; j += 4) {
        int s0 = esrc[j], s1 = esrc[j + 1], s2 = esrc[j + 2], s3 = esrc[j + 3];
        float v0 = hs2[(size_t)s0 * C_OUT + c];
        float v1 = hs2[(size_t)s1 * C_OUT + c];
        float v2 = hs2[(size_t)s2 * C_OUT + c];
        float v3 = hs2[(size_t)s3 * C_OUT + c];
        acc += (v0 + v1) + (v2 + v3);
    }
    for (; j < end; ++j) acc += hs2[(size_t)esrc[j] * C_OUT + c];
    out[(size_t)node * C_OUT + c] = fmaf(dinv[node], acc, b2[c]);
}

extern "C" void kernel_launch(void* const* d_in, const int* in_sizes, int n_in,
                              void* d_out, int out_size, void* d_ws, size_t ws_size,
                              hipStream_t stream) {
    const float* x  = (const float*)d_in[0];
    const unsigned int* ei = (const unsigned int*)d_in[1];
    const float* W1 = (const float*)d_in[2];
    const float* b1 = (const float*)d_in[3];
    const float* W2 = (const float*)d_in[4];
    const float* b2 = (const float*)d_in[5];
    float* out = (float*)d_out;

    char* ws = (char*)d_ws;
    size_t off = 0;
    auto take = [&](size_t bytes) {
        char* p = ws + off;
        off += (bytes + 255) & ~(size_t)255;
        return p;
    };
    int*   flag     = (int*)  take(256);
    int*   esrc     = (int*)  take((size_t)N_EDGES * 4);
    int*   rank     = (int*)  take((size_t)N_EDGES * 4);
    int*   deg      = (int*)  take((size_t)N_NODES * 4);
    int*   rowstart = (int*)  take((size_t)(N_NODES + 1) * 4);
    int*   blksum   = (int*)  take((size_t)NB1 * 4);
    int*   blkoff   = (int*)  take((size_t)NB1 * 4);
    float* dinv     = (float*)take((size_t)N_NODES * 4);
    float* hs1      = (float*)take((size_t)N_NODES * C_HID * 4);
    float* y1       = (float*)take((size_t)N_NODES * C_HID * 4);
    float* hs2      = (float*)take((size_t)N_NODES * C_OUT * 4);

    // Rank pass: degree histogram + per-edge rank in one atomic sweep
    k_detect<<<1, 64, 0, stream>>>(ei, flag);
    hipMemsetAsync(deg, 0, (size_t)N_NODES * 4, stream);
    k_rank<<<1024, 256, 0, stream>>>(ei, flag, deg, rank);

    // CSR offsets: scan degrees (+ dinv)
    k_scan1<<<NB1, 256, 0, stream>>>(deg, rowstart, blksum, dinv);
    k_scan2<<<1, 512, 0, stream>>>(blksum, blkoff);
    k_scan3<<<NB1, 256, 0, stream>>>(rowstart, blkoff);

    // Atomic-free fill with non-temporal scatter stores
    k_fill2<<<1024, 256, 0, stream>>>(ei, flag, rowstart, rank, esrc);

    // Layer 1
    k_gemm1<<<GT_BLOCKS, 256, 0, stream>>>(x, W1, dinv, hs1);
    k_agg1<<<N_NODES / 4, 256, 0, stream>>>(rowstart, esrc, hs1, dinv, b1, y1);

    // Layer 2
    k_gemm2<<<GT_BLOCKS, 256, 0, stream>>>(y1, W2, dinv, hs2);
    k_agg2<<<N_NODES / 8, 256, 0, stream>>>(rowstart, esrc, hs2, dinv, b2, out);
}

// Round 7
// 310.666 us; speedup vs baseline: 2.0317x; 1.0013x over previous
//
#include <hip/hip_runtime.h>
#include <hip/hip_fp16.h>

#define N_NODES 100000
#define N_EDGES 1000000
#define C_IN 128
#define C_HID 64
#define C_OUT 32
#define NB1 ((N_NODES + 255) / 256)      // 391 scan blocks
#define GT_BLOCKS ((N_NODES + 63) / 64)  // 1563 tiles of 64 rows

// ---------------------------------------------------------------------------
// Edge-index dtype detection (int64 vs int32 storage).
// ---------------------------------------------------------------------------
__global__ __launch_bounds__(64) void k_detect(const unsigned int* __restrict__ ei,
                                               int* __restrict__ flag) {
    if (threadIdx.x == 0 && blockIdx.x == 0) {
        int is64 = 1;
        for (int i = 0; i < 64; ++i)
            if (ei[2 * i + 1] != 0u) { is64 = 0; break; }
        *flag = is64;
    }
}

// ---------------------------------------------------------------------------
// Rank pass: ONE atomic pass builds the degree histogram AND per-edge rank.
// ---------------------------------------------------------------------------
__global__ __launch_bounds__(256) void k_rank(const unsigned int* __restrict__ ei,
                                              const int* __restrict__ flag,
                                              int* __restrict__ deg,
                                              int* __restrict__ rank) {
    const int T = gridDim.x * 256;
    const int t = blockIdx.x * 256 + threadIdx.x;
    const bool is64 = (*flag != 0);
    int d[4];
#pragma unroll
    for (int i = 0; i < 4; ++i) {
        int e = t + i * T;
        if (e < N_EDGES)
            d[i] = is64 ? ((const int2*)ei)[(size_t)N_EDGES + e].x
                        : (int)ei[(size_t)N_EDGES + e];
    }
    int r[4];
#pragma unroll
    for (int i = 0; i < 4; ++i) {
        int e = t + i * T;
        if (e < N_EDGES) r[i] = atomicAdd(&deg[d[i]], 1);
    }
#pragma unroll
    for (int i = 0; i < 4; ++i) {
        int e = t + i * T;
        if (e < N_EDGES) __builtin_nontemporal_store(r[i], &rank[e]);
    }
}

// ---------------------------------------------------------------------------
// 3-kernel exclusive prefix scan of deg -> rowstart; also dinv = rsqrt(deg+1).
// ---------------------------------------------------------------------------
__global__ __launch_bounds__(256) void k_scan1(const int* __restrict__ deg,
                                               int* __restrict__ rowstart,
                                               int* __restrict__ blksum,
                                               float* __restrict__ dinv) {
    __shared__ int sm[256];
    int i = blockIdx.x * 256 + threadIdx.x;
    int v = (i < N_NODES) ? deg[i] : 0;
    if (i < N_NODES) dinv[i] = rsqrtf((float)v + 1.0f);
    sm[threadIdx.x] = v;
    __syncthreads();
    for (int o = 1; o < 256; o <<= 1) {
        int t = (threadIdx.x >= o) ? sm[threadIdx.x - o] : 0;
        __syncthreads();
        sm[threadIdx.x] += t;
        __syncthreads();
    }
    if (i < N_NODES) rowstart[i] = sm[threadIdx.x] - v;   // exclusive, block-local
    if (threadIdx.x == 255) blksum[blockIdx.x] = sm[255];
}

__global__ __launch_bounds__(512) void k_scan2(const int* __restrict__ blksum,
                                               int* __restrict__ blkoff) {
    __shared__ int sm[512];
    int v = (threadIdx.x < NB1) ? blksum[threadIdx.x] : 0;
    sm[threadIdx.x] = v;
    __syncthreads();
    for (int o = 1; o < 512; o <<= 1) {
        int t = (threadIdx.x >= o) ? sm[threadIdx.x - o] : 0;
        __syncthreads();
        sm[threadIdx.x] += t;
        __syncthreads();
    }
    if (threadIdx.x < NB1) blkoff[threadIdx.x] = sm[threadIdx.x] - v;  // exclusive
}

__global__ __launch_bounds__(256) void k_scan3(int* __restrict__ rowstart,
                                               const int* __restrict__ blkoff) {
    int i = blockIdx.x * 256 + threadIdx.x;
    if (i < N_NODES) rowstart[i] += blkoff[i >> 8];
    if (i == 0) rowstart[N_NODES] = N_EDGES;
}

// ---------------------------------------------------------------------------
// Fill pass: p = rowstart[dst] + rank[e]; esrc[p] = src. No atomics; NT store.
// ---------------------------------------------------------------------------
__global__ __launch_bounds__(256) void k_fill2(const unsigned int* __restrict__ ei,
                                               const int* __restrict__ flag,
                                               const int* __restrict__ rowstart,
                                               const int* __restrict__ rank,
                                               int* __restrict__ esrc) {
    const int T = gridDim.x * 256;
    const int t = blockIdx.x * 256 + threadIdx.x;
    const bool is64 = (*flag != 0);
#pragma unroll
    for (int i = 0; i < 4; ++i) {
        int e = t + i * T;
        if (e < N_EDGES) {
            int s, d;
            if (is64) {
                s = ((const int2*)ei)[e].x;
                d = ((const int2*)ei)[(size_t)N_EDGES + e].x;
            } else {
                s = (int)ei[e];
                d = (int)ei[(size_t)N_EDGES + e];
            }
            int p = rowstart[d] + rank[e];
            __builtin_nontemporal_store(s, &esrc[p]);
        }
    }
}

// ---------------------------------------------------------------------------
// GEMM1: hs1[n][c] = (x[n][:] @ W1)[c] * dinv[n]    (128 -> 64), fp16 out.
// LDS-staged x tile (R6 win). Epilogue packs channel pairs to __half2 --
// halves the agg1 gather volume (R6: FETCH 5x footprint, L2 thrash).
// ---------------------------------------------------------------------------
__global__ __launch_bounds__(256) void k_gemm1(const float* __restrict__ x,
                                               const float* __restrict__ W1,
                                               const float* __restrict__ dinv,
                                               __half* __restrict__ hs1h) {
    __shared__ float w[C_IN * C_HID];   // 32 KB
    __shared__ float xt[64 * C_IN];     // 32 KB
    const int t = threadIdx.x;
    {
        const float4* W4 = (const float4*)W1;
        const float4* x4g = (const float4*)x;
        float4* w4 = (float4*)w;
        float4* xt4w = (float4*)xt;
        const size_t base = (size_t)blockIdx.x * 64 * (C_IN / 4);
        const size_t xmax = (size_t)N_NODES * (C_IN / 4) - 1;
#pragma unroll
        for (int j = 0; j < 8; ++j) {
            size_t idx = base + t + j * 256;
            if (idx > xmax) idx = xmax;            // tail clamp (dup reads ok)
            xt4w[t + j * 256] = x4g[idx];
            w4[t + j * 256] = W4[t + j * 256];
        }
    }
    __syncthreads();
    const int c2 = t & 31;          // channel pair
    const int h  = (t >> 5) & 1;    // half-wave -> row group
    const int wid = t >> 6;
    const int lrow0 = wid * 16 + h * 8;
    const int grow0 = blockIdx.x * 64 + lrow0;
    const float4* xt4 = (const float4*)xt;

    float acc0[8] = {0, 0, 0, 0, 0, 0, 0, 0};
    float acc1[8] = {0, 0, 0, 0, 0, 0, 0, 0};
#pragma unroll 2
    for (int k4 = 0; k4 < C_IN / 4; ++k4) {
        float4 xv[8];
#pragma unroll
        for (int r = 0; r < 8; ++r)
            xv[r] = xt4[(lrow0 + r) * (C_IN / 4) + k4];   // LDS broadcast
        float2 wv[4];
#pragma unroll
        for (int j = 0; j < 4; ++j)
            wv[j] = *reinterpret_cast<const float2*>(&w[(k4 * 4 + j) * C_HID + 2 * c2]);
#pragma unroll
        for (int r = 0; r < 8; ++r) {
            acc0[r] = fmaf(xv[r].x, wv[0].x, acc0[r]);
            acc1[r] = fmaf(xv[r].x, wv[0].y, acc1[r]);
            acc0[r] = fmaf(xv[r].y, wv[1].x, acc0[r]);
            acc1[r] = fmaf(xv[r].y, wv[1].y, acc1[r]);
            acc0[r] = fmaf(xv[r].z, wv[2].x, acc0[r]);
            acc1[r] = fmaf(xv[r].z, wv[2].y, acc1[r]);
            acc0[r] = fmaf(xv[r].w, wv[3].x, acc0[r]);
            acc1[r] = fmaf(xv[r].w, wv[3].y, acc1[r]);
        }
    }
    __half2* h2o = (__half2*)hs1h;
#pragma unroll
    for (int r = 0; r < 8; ++r) {
        int rr = grow0 + r;
        if (rr < N_NODES) {
            float dv = dinv[rr];
            h2o[(size_t)rr * 32 + c2] = __floats2half2_rn(acc0[r] * dv, acc1[r] * dv);
        }
    }
}

// ---------------------------------------------------------------------------
// Agg1 (+fused epilogue): y1 = relu(dinv*(Σ hs1[src] + hs1[n]) + b1)
// Wave = 1 node; half-wave = 1 edge (lane&31 = __half2 channel pair).
// One wave load instr covers 2 edges (256B) -> 2x edges in flight vs R6.
// fp32 accumulate; cross-half combine via shfl_xor(32).
// ---------------------------------------------------------------------------
__global__ __launch_bounds__(256) void k_agg1(const int* __restrict__ rowstart,
                                              const int* __restrict__ esrc,
                                              const __half* __restrict__ hs1h,
                                              const float* __restrict__ dinv,
                                              const float* __restrict__ b1,
                                              float* __restrict__ y1) {
    const int node = blockIdx.x * 4 + (threadIdx.x >> 6);
    const int lane = threadIdx.x & 63;
    const int c2 = lane & 31;
    const int eo = lane >> 5;
    const __half2* h2 = (const __half2*)hs1h;
    const int beg = rowstart[node], end = rowstart[node + 1];
    float2 acc; acc.x = 0.f; acc.y = 0.f;
    int j = beg + eo;
    for (; j + 6 < end; j += 8) {     // 4 edges per lane-group, 8 per wave
        int s0 = esrc[j], s1 = esrc[j + 2], s2 = esrc[j + 4], s3 = esrc[j + 6];
        float2 v0 = __half22float2(h2[(size_t)s0 * 32 + c2]);
        float2 v1 = __half22float2(h2[(size_t)s1 * 32 + c2]);
        float2 v2 = __half22float2(h2[(size_t)s2 * 32 + c2]);
        float2 v3 = __half22float2(h2[(size_t)s3 * 32 + c2]);
        acc.x += (v0.x + v1.x) + (v2.x + v3.x);
        acc.y += (v0.y + v1.y) + (v2.y + v3.y);
    }
    for (; j < end; j += 2) {
        float2 v = __half22float2(h2[(size_t)esrc[j] * 32 + c2]);
        acc.x += v.x; acc.y += v.y;
    }
    acc.x += __shfl_xor(acc.x, 32);
    acc.y += __shfl_xor(acc.y, 32);
    if (eo == 0) {
        float2 self = __half22float2(h2[(size_t)node * 32 + c2]);
        float dv = dinv[node];
        float2 o;
        o.x = fmaxf(fmaf(dv, acc.x + self.x, b1[2 * c2]), 0.f);
        o.y = fmaxf(fmaf(dv, acc.y + self.y, b1[2 * c2 + 1]), 0.f);
        reinterpret_cast<float2*>(y1)[(size_t)node * 32 + c2] = o;
    }
}

// ---------------------------------------------------------------------------
// GEMM2: hs2[n][c] = (y1[n][:] @ W2)[c] * dinv[n]    (64 -> 32), fp16 out.
// Lane = channel pair (16) x row-group (4 rows); wave = 16 rows.
// ---------------------------------------------------------------------------
__global__ __launch_bounds__(256) void k_gemm2(const float* __restrict__ y1,
                                               const float* __restrict__ W2,
                                               const float* __restrict__ dinv,
                                               __half* __restrict__ hs2h) {
    __shared__ float w[C_HID * C_OUT];   // 8 KB
    __shared__ float yt[64 * C_HID];     // 16 KB
    const int t = threadIdx.x;
    {
        const float4* W4 = (const float4*)W2;
        const float4* y4g = (const float4*)y1;
        float4* w4 = (float4*)w;
        float4* yt4w = (float4*)yt;
        const size_t base = (size_t)blockIdx.x * 64 * (C_HID / 4);
        const size_t ymax = (size_t)N_NODES * (C_HID / 4) - 1;
#pragma unroll
        for (int j = 0; j < 4; ++j) {
            size_t idx = base + t + j * 256;
            if (idx > ymax) idx = ymax;
            yt4w[t + j * 256] = y4g[idx];
        }
#pragma unroll
        for (int j = 0; j < 2; ++j)
            w4[t + j * 256] = W4[t + j * 256];
    }
    __syncthreads();
    const int c2 = t & 15;               // channel pair 0..15
    const int rg = (t >> 4) & 3;         // row group within wave
    const int wid = t >> 6;
    const int lrow0 = wid * 16 + rg * 4; // wave covers 16 rows; block 64
    const int grow0 = blockIdx.x * 64 + lrow0;
    const float4* yt4 = (const float4*)yt;

    float2 acc[4];
#pragma unroll
    for (int r = 0; r < 4; ++r) { acc[r].x = 0.f; acc[r].y = 0.f; }
#pragma unroll 2
    for (int k4 = 0; k4 < C_HID / 4; ++k4) {
        float4 yv[4];
#pragma unroll
        for (int r = 0; r < 4; ++r)
            yv[r] = yt4[(lrow0 + r) * (C_HID / 4) + k4];
        float2 wv[4];
#pragma unroll
        for (int j = 0; j < 4; ++j)
            wv[j] = *reinterpret_cast<const float2*>(&w[(k4 * 4 + j) * C_OUT + 2 * c2]);
#pragma unroll
        for (int r = 0; r < 4; ++r) {
            acc[r].x = fmaf(yv[r].x, wv[0].x, acc[r].x);
            acc[r].y = fmaf(yv[r].x, wv[0].y, acc[r].y);
            acc[r].x = fmaf(yv[r].y, wv[1].x, acc[r].x);
            acc[r].y = fmaf(yv[r].y, wv[1].y, acc[r].y);
            acc[r].x = fmaf(yv[r].z, wv[2].x, acc[r].x);
            acc[r].y = fmaf(yv[r].z, wv[2].y, acc[r].y);
            acc[r].x = fmaf(yv[r].w, wv[3].x, acc[r].x);
            acc[r].y = fmaf(yv[r].w, wv[3].y, acc[r].y);
        }
    }
    __half2* h2o = (__half2*)hs2h;
#pragma unroll
    for (int r = 0; r < 4; ++r) {
        int rr = grow0 + r;
        if (rr < N_NODES) {
            float dv = dinv[rr];
            h2o[(size_t)rr * 16 + c2] = __floats2half2_rn(acc[r].x * dv, acc[r].y * dv);
        }
    }
}

// ---------------------------------------------------------------------------
// Agg2 (+fused epilogue, no relu): out = dinv*(Σ hs2[src] + hs2[n]) + b2
// Wave = 1 node; quarter-wave = 1 edge (lane&15 = channel pair) -> one wave
// load instr covers 4 edges. Combine via shfl_xor(16)+shfl_xor(32).
// ---------------------------------------------------------------------------
__global__ __launch_bounds__(256) void k_agg2(const int* __restrict__ rowstart,
                                              const int* __restrict__ esrc,
                                              const __half* __restrict__ hs2h,
                                              const float* __restrict__ dinv,
                                              const float* __restrict__ b2,
                                              float* __restrict__ out) {
    const int node = blockIdx.x * 4 + (threadIdx.x >> 6);
    const int lane = threadIdx.x & 63;
    const int c2 = lane & 15;
    const int eo = lane >> 4;
    const __half2* h2 = (const __half2*)hs2h;
    const int beg = rowstart[node], end = rowstart[node + 1];
    float2 acc; acc.x = 0.f; acc.y = 0.f;
    int j = beg + eo;
    for (; j + 12 < end; j += 16) {   // 4 edges per lane-group, 16 per wave
        int s0 = esrc[j], s1 = esrc[j + 4], s2 = esrc[j + 8], s3 = esrc[j + 12];
        float2 v0 = __half22float2(h2[(size_t)s0 * 16 + c2]);
        float2 v1 = __half22float2(h2[(size_t)s1 * 16 + c2]);
        float2 v2 = __half22float2(h2[(size_t)s2 * 16 + c2]);
        float2 v3 = __half22float2(h2[(size_t)s3 * 16 + c2]);
        acc.x += (v0.x + v1.x) + (v2.x + v3.x);
        acc.y += (v0.y + v1.y) + (v2.y + v3.y);
    }
    for (; j < end; j += 4) {
        float2 v = __half22float2(h2[(size_t)esrc[j] * 16 + c2]);
        acc.x += v.x; acc.y += v.y;
    }
    acc.x += __shfl_xor(acc.x, 16);
    acc.y += __shfl_xor(acc.y, 16);
    acc.x += __shfl_xor(acc.x, 32);
    acc.y += __shfl_xor(acc.y, 32);
    if (eo == 0) {
        float2 self = __half22float2(h2[(size_t)node * 16 + c2]);
        float dv = dinv[node];
        float2 o;
        o.x = fmaf(dv, acc.x + self.x, b2[2 * c2]);
        o.y = fmaf(dv, acc.y + self.y, b2[2 * c2 + 1]);
        reinterpret_cast<float2*>(out)[(size_t)node * 16 + c2] = o;
    }
}

extern "C" void kernel_launch(void* const* d_in, const int* in_sizes, int n_in,
                              void* d_out, int out_size, void* d_ws, size_t ws_size,
                              hipStream_t stream) {
    const float* x  = (const float*)d_in[0];
    const unsigned int* ei = (const unsigned int*)d_in[1];
    const float* W1 = (const float*)d_in[2];
    const float* b1 = (const float*)d_in[3];
    const float* W2 = (const float*)d_in[4];
    const float* b2 = (const float*)d_in[5];
    float* out = (float*)d_out;

    char* ws = (char*)d_ws;
    size_t off = 0;
    auto take = [&](size_t bytes) {
        char* p = ws + off;
        off += (bytes + 255) & ~(size_t)255;
        return p;
    };
    int*    flag     = (int*)   take(256);
    int*    esrc     = (int*)   take((size_t)N_EDGES * 4);
    int*    rank     = (int*)   take((size_t)N_EDGES * 4);
    int*    deg      = (int*)   take((size_t)N_NODES * 4);
    int*    rowstart = (int*)   take((size_t)(N_NODES + 1) * 4);
    int*    blksum   = (int*)   take((size_t)NB1 * 4);
    int*    blkoff   = (int*)   take((size_t)NB1 * 4);
    float*  dinv     = (float*) take((size_t)N_NODES * 4);
    __half* hs1h     = (__half*)take((size_t)N_NODES * C_HID * 2);
    float*  y1       = (float*) take((size_t)N_NODES * C_HID * 4);
    __half* hs2h     = (__half*)take((size_t)N_NODES * C_OUT * 2);

    // Rank pass: degree histogram + per-edge rank in one atomic sweep
    k_detect<<<1, 64, 0, stream>>>(ei, flag);
    hipMemsetAsync(deg, 0, (size_t)N_NODES * 4, stream);
    k_rank<<<1024, 256, 0, stream>>>(ei, flag, deg, rank);

    // CSR offsets: scan degrees (+ dinv)
    k_scan1<<<NB1, 256, 0, stream>>>(deg, rowstart, blksum, dinv);
    k_scan2<<<1, 512, 0, stream>>>(blksum, blkoff);
    k_scan3<<<NB1, 256, 0, stream>>>(rowstart, blkoff);

    // Atomic-free fill with non-temporal scatter stores
    k_fill2<<<1024, 256, 0, stream>>>(ei, flag, rowstart, rank, esrc);

    // Layer 1
    k_gemm1<<<GT_BLOCKS, 256, 0, stream>>>(x, W1, dinv, hs1h);
    k_agg1<<<N_NODES / 4, 256, 0, stream>>>(rowstart, esrc, hs1h, dinv, b1, y1);

    // Layer 2
    k_gemm2<<<GT_BLOCKS, 256, 0, stream>>>(y1, W2, dinv, hs2h);
    k_agg2<<<N_NODES / 4, 256, 0, stream>>>(rowstart, esrc, hs2h, dinv, b2, out);
}

// Round 8
// 291.838 us; speedup vs baseline: 2.1628x; 1.0645x over previous
//
#include <hip/hip_runtime.h>
#include <hip/hip_fp16.h>

#define N_NODES 100000
#define N_EDGES 1000000
#define C_IN 128
#define C_HID 64
#define C_OUT 32
#define NB1 ((N_NODES + 255) / 256)      // 391 scan blocks
#define GT_BLOCKS ((N_NODES + 63) / 64)  // 1563 gemm1 tiles of 64 rows
#define AGG1_BLOCKS 6250                 // 4 waves/block -> 4 nodes per wave

// ---------------------------------------------------------------------------
// Edge-index dtype detection (int64 vs int32 storage).
// ---------------------------------------------------------------------------
__global__ __launch_bounds__(64) void k_detect(const unsigned int* __restrict__ ei,
                                               int* __restrict__ flag) {
    if (threadIdx.x == 0 && blockIdx.x == 0) {
        int is64 = 1;
        for (int i = 0; i < 64; ++i)
            if (ei[2 * i + 1] != 0u) { is64 = 0; break; }
        *flag = is64;
    }
}

// ---------------------------------------------------------------------------
// Rank pass: ONE atomic pass builds the degree histogram AND per-edge rank.
// ---------------------------------------------------------------------------
__global__ __launch_bounds__(256) void k_rank(const unsigned int* __restrict__ ei,
                                              const int* __restrict__ flag,
                                              int* __restrict__ deg,
                                              int* __restrict__ rank) {
    const int T = gridDim.x * 256;
    const int t = blockIdx.x * 256 + threadIdx.x;
    const bool is64 = (*flag != 0);
    int d[4];
#pragma unroll
    for (int i = 0; i < 4; ++i) {
        int e = t + i * T;
        if (e < N_EDGES)
            d[i] = is64 ? ((const int2*)ei)[(size_t)N_EDGES + e].x
                        : (int)ei[(size_t)N_EDGES + e];
    }
    int r[4];
#pragma unroll
    for (int i = 0; i < 4; ++i) {
        int e = t + i * T;
        if (e < N_EDGES) r[i] = atomicAdd(&deg[d[i]], 1);
    }
#pragma unroll
    for (int i = 0; i < 4; ++i) {
        int e = t + i * T;
        if (e < N_EDGES) __builtin_nontemporal_store(r[i], &rank[e]);
    }
}

// ---------------------------------------------------------------------------
// 3-kernel exclusive prefix scan of deg -> rowstart; also dinv = rsqrt(deg+1).
// ---------------------------------------------------------------------------
__global__ __launch_bounds__(256) void k_scan1(const int* __restrict__ deg,
                                               int* __restrict__ rowstart,
                                               int* __restrict__ blksum,
                                               float* __restrict__ dinv) {
    __shared__ int sm[256];
    int i = blockIdx.x * 256 + threadIdx.x;
    int v = (i < N_NODES) ? deg[i] : 0;
    if (i < N_NODES) dinv[i] = rsqrtf((float)v + 1.0f);
    sm[threadIdx.x] = v;
    __syncthreads();
    for (int o = 1; o < 256; o <<= 1) {
        int t = (threadIdx.x >= o) ? sm[threadIdx.x - o] : 0;
        __syncthreads();
        sm[threadIdx.x] += t;
        __syncthreads();
    }
    if (i < N_NODES) rowstart[i] = sm[threadIdx.x] - v;   // exclusive, block-local
    if (threadIdx.x == 255) blksum[blockIdx.x] = sm[255];
}

__global__ __launch_bounds__(512) void k_scan2(const int* __restrict__ blksum,
                                               int* __restrict__ blkoff) {
    __shared__ int sm[512];
    int v = (threadIdx.x < NB1) ? blksum[threadIdx.x] : 0;
    sm[threadIdx.x] = v;
    __syncthreads();
    for (int o = 1; o < 512; o <<= 1) {
        int t = (threadIdx.x >= o) ? sm[threadIdx.x - o] : 0;
        __syncthreads();
        sm[threadIdx.x] += t;
        __syncthreads();
    }
    if (threadIdx.x < NB1) blkoff[threadIdx.x] = sm[threadIdx.x] - v;  // exclusive
}

__global__ __launch_bounds__(256) void k_scan3(int* __restrict__ rowstart,
                                               const int* __restrict__ blkoff) {
    int i = blockIdx.x * 256 + threadIdx.x;
    if (i < N_NODES) rowstart[i] += blkoff[i >> 8];
    if (i == 0) rowstart[N_NODES] = N_EDGES;
}

// ---------------------------------------------------------------------------
// Fill pass: p = rowstart[dst] + rank[e]; esrc[p] = src. No atomics; NT store.
// ---------------------------------------------------------------------------
__global__ __launch_bounds__(256) void k_fill2(const unsigned int* __restrict__ ei,
                                               const int* __restrict__ flag,
                                               const int* __restrict__ rowstart,
                                               const int* __restrict__ rank,
                                               int* __restrict__ esrc) {
    const int T = gridDim.x * 256;
    const int t = blockIdx.x * 256 + threadIdx.x;
    const bool is64 = (*flag != 0);
#pragma unroll
    for (int i = 0; i < 4; ++i) {
        int e = t + i * T;
        if (e < N_EDGES) {
            int s, d;
            if (is64) {
                s = ((const int2*)ei)[e].x;
                d = ((const int2*)ei)[(size_t)N_EDGES + e].x;
            } else {
                s = (int)ei[e];
                d = (int)ei[(size_t)N_EDGES + e];
            }
            int p = rowstart[d] + rank[e];
            __builtin_nontemporal_store(s, &esrc[p]);
        }
    }
}

// ---------------------------------------------------------------------------
// GEMM1: hs1[n][c] = (x[n][:] @ W1)[c] * dinv[n]    (128 -> 64), fp16 out.
// LDS-staged x tile (R6 win); fp16 pack halves agg gather volume (R7 win).
// ---------------------------------------------------------------------------
__global__ __launch_bounds__(256) void k_gemm1(const float* __restrict__ x,
                                               const float* __restrict__ W1,
                                               const float* __restrict__ dinv,
                                               __half* __restrict__ hs1h) {
    __shared__ float w[C_IN * C_HID];   // 32 KB
    __shared__ float xt[64 * C_IN];     // 32 KB
    const int t = threadIdx.x;
    {
        const float4* W4 = (const float4*)W1;
        const float4* x4g = (const float4*)x;
        float4* w4 = (float4*)w;
        float4* xt4w = (float4*)xt;
        const size_t base = (size_t)blockIdx.x * 64 * (C_IN / 4);
        const size_t xmax = (size_t)N_NODES * (C_IN / 4) - 1;
#pragma unroll
        for (int j = 0; j < 8; ++j) {
            size_t idx = base + t + j * 256;
            if (idx > xmax) idx = xmax;            // tail clamp (dup reads ok)
            xt4w[t + j * 256] = x4g[idx];
            w4[t + j * 256] = W4[t + j * 256];
        }
    }
    __syncthreads();
    const int c2 = t & 31;          // channel pair
    const int h  = (t >> 5) & 1;    // half-wave -> row group
    const int wid = t >> 6;
    const int lrow0 = wid * 16 + h * 8;
    const int grow0 = blockIdx.x * 64 + lrow0;
    const float4* xt4 = (const float4*)xt;

    float acc0[8] = {0, 0, 0, 0, 0, 0, 0, 0};
    float acc1[8] = {0, 0, 0, 0, 0, 0, 0, 0};
#pragma unroll 2
    for (int k4 = 0; k4 < C_IN / 4; ++k4) {
        float4 xv[8];
#pragma unroll
        for (int r = 0; r < 8; ++r)
            xv[r] = xt4[(lrow0 + r) * (C_IN / 4) + k4];   // LDS broadcast
        float2 wv[4];
#pragma unroll
        for (int j = 0; j < 4; ++j)
            wv[j] = *reinterpret_cast<const float2*>(&w[(k4 * 4 + j) * C_HID + 2 * c2]);
#pragma unroll
        for (int r = 0; r < 8; ++r) {
            acc0[r] = fmaf(xv[r].x, wv[0].x, acc0[r]);
            acc1[r] = fmaf(xv[r].x, wv[0].y, acc1[r]);
            acc0[r] = fmaf(xv[r].y, wv[1].x, acc0[r]);
            acc1[r] = fmaf(xv[r].y, wv[1].y, acc1[r]);
            acc0[r] = fmaf(xv[r].z, wv[2].x, acc0[r]);
            acc1[r] = fmaf(xv[r].z, wv[2].y, acc1[r]);
            acc0[r] = fmaf(xv[r].w, wv[3].x, acc0[r]);
            acc1[r] = fmaf(xv[r].w, wv[3].y, acc1[r]);
        }
    }
    __half2* h2o = (__half2*)hs1h;
#pragma unroll
    for (int r = 0; r < 8; ++r) {
        int rr = grow0 + r;
        if (rr < N_NODES) {
            float dv = dinv[rr];
            h2o[(size_t)rr * 32 + c2] = __floats2half2_rn(acc0[r] * dv, acc1[r] * dv);
        }
    }
}

// ---------------------------------------------------------------------------
// FUSED agg1 + layer-1 epilogue + GEMM2:
//   y = relu(dinv*(Σ hs1[src] + hs1[n]) + b1)   (in regs/LDS, never global)
//   hs2h[n] = (y @ W2) * dinv[n]                (fp16 out for agg2)
// Wave = 1 node/iter, grid-stride (~4 nodes/wave -> cross-node pipelining).
// Gather: 2 half-waves x 8 predicated slots = 16 edges per iteration, all
// loads independent -> ONE latency stall per node (R7: per-edge time const
// => per-node serialization was the wall). Unused slots clamp to beg.
// Matvec: W2 register-resident (32 VGPR/lane, k split by half-wave); y-row
// via 256B per-wave LDS buffer; shfl_xor(32) combines k-halves.
// ---------------------------------------------------------------------------
__global__ __launch_bounds__(256) void k_agg1g2(const int* __restrict__ rowstart,
                                                const int* __restrict__ esrc,
                                                const __half* __restrict__ hs1h,
                                                const float* __restrict__ dinv,
                                                const float* __restrict__ b1,
                                                const float* __restrict__ W2,
                                                __half* __restrict__ hs2h) {
    __shared__ float2 yrow[4][32];      // per-wave y-row buffer
    const int wid = threadIdx.x >> 6;
    const int lane = threadIdx.x & 63;
    const int c2 = lane & 31;           // layer1 channel-pair; layer2 out-channel
    const int eo = lane >> 5;           // half-wave index
    // W2 -> registers: Wreg[2kk+p] = W2[(32*eo + 2*kk + p)][c2], k-half per eo
    float Wreg[32];
#pragma unroll
    for (int kk = 0; kk < 16; ++kk) {
        Wreg[2 * kk]     = W2[(32 * eo + 2 * kk) * C_OUT + c2];
        Wreg[2 * kk + 1] = W2[(32 * eo + 2 * kk + 1) * C_OUT + c2];
    }
    const __half2* h2 = (const __half2*)hs1h;
    const float2 bb = { b1[2 * c2], b1[2 * c2 + 1] };
    const int waveId = blockIdx.x * 4 + wid;

    for (int node = waveId; node < N_NODES; node += AGG1_BLOCKS * 4) {
        const int beg = rowstart[node], end = rowstart[node + 1];
        float2 acc; acc.x = 0.f; acc.y = 0.f;
        for (int j0 = beg; j0 < end; j0 += 16) {
            const int jj = j0 + eo;
            int idx[8];
#pragma unroll
            for (int s = 0; s < 8; ++s) {
                int j = jj + 2 * s;
                idx[s] = esrc[j < end ? j : beg];   // clamp: dup load, L1 hit
            }
            float2 v[8];
#pragma unroll
            for (int s = 0; s < 8; ++s)
                v[s] = __half22float2(h2[(size_t)idx[s] * 32 + c2]);
#pragma unroll
            for (int s = 0; s < 8; ++s) {
                if (jj + 2 * s < end) { acc.x += v[s].x; acc.y += v[s].y; }
            }
        }
        acc.x += __shfl_xor(acc.x, 32);
        acc.y += __shfl_xor(acc.y, 32);
        // layer-1 epilogue (y never leaves the CU)
        const float dv = dinv[node];
        float2 self = __half22float2(h2[(size_t)node * 32 + c2]);
        float2 y;
        y.x = fmaxf(fmaf(dv, acc.x + self.x, bb.x), 0.f);
        y.y = fmaxf(fmaf(dv, acc.y + self.y, bb.y), 0.f);
        yrow[wid][c2] = y;              // both halves write same value (benign)
        __builtin_amdgcn_wave_barrier();
        // layer-2 matvec: out[c2] = Σ_k y[k] * W2[k][c2], k-half per eo
        float o = 0.f;
#pragma unroll
        for (int kk = 0; kk < 16; ++kk) {
            float2 yv = yrow[wid][16 * eo + kk];
            o = fmaf(yv.x, Wreg[2 * kk], o);
            o = fmaf(yv.y, Wreg[2 * kk + 1], o);
        }
        __builtin_amdgcn_wave_barrier();
        o += __shfl_xor(o, 32);
        if (eo == 0)
            hs2h[(size_t)node * C_OUT + c2] = __float2half(o * dv);
    }
}

// ---------------------------------------------------------------------------
// Agg2 (+fused epilogue, no relu): out = dinv*(Σ hs2[src] + hs2[n]) + b2
// Wave = 1 node; 4 quarter-waves x 4 predicated slots = 16 edges/iter,
// no serial tail (clamp unused slots to beg).
// ---------------------------------------------------------------------------
__global__ __launch_bounds__(256) void k_agg2(const int* __restrict__ rowstart,
                                              const int* __restrict__ esrc,
                                              const __half* __restrict__ hs2h,
                                              const float* __restrict__ dinv,
                                              const float* __restrict__ b2,
                                              float* __restrict__ out) {
    const int node = blockIdx.x * 4 + (threadIdx.x >> 6);
    const int lane = threadIdx.x & 63;
    const int c2 = lane & 15;
    const int eo = lane >> 4;
    const __half2* h2 = (const __half2*)hs2h;
    const int beg = rowstart[node], end = rowstart[node + 1];
    float2 acc; acc.x = 0.f; acc.y = 0.f;
    for (int j0 = beg; j0 < end; j0 += 16) {
        const int jj = j0 + eo;
        int idx[4];
#pragma unroll
        for (int s = 0; s < 4; ++s) {
            int j = jj + 4 * s;
            idx[s] = esrc[j < end ? j : beg];
        }
        float2 v[4];
#pragma unroll
        for (int s = 0; s < 4; ++s)
            v[s] = __half22float2(h2[(size_t)idx[s] * 16 + c2]);
#pragma unroll
        for (int s = 0; s < 4; ++s) {
            if (jj + 4 * s < end) { acc.x += v[s].x; acc.y += v[s].y; }
        }
    }
    acc.x += __shfl_xor(acc.x, 16);
    acc.y += __shfl_xor(acc.y, 16);
    acc.x += __shfl_xor(acc.x, 32);
    acc.y += __shfl_xor(acc.y, 32);
    if (eo == 0) {
        float2 self = __half22float2(h2[(size_t)node * 16 + c2]);
        float dv = dinv[node];
        float2 o;
        o.x = fmaf(dv, acc.x + self.x, b2[2 * c2]);
        o.y = fmaf(dv, acc.y + self.y, b2[2 * c2 + 1]);
        reinterpret_cast<float2*>(out)[(size_t)node * 16 + c2] = o;
    }
}

extern "C" void kernel_launch(void* const* d_in, const int* in_sizes, int n_in,
                              void* d_out, int out_size, void* d_ws, size_t ws_size,
                              hipStream_t stream) {
    const float* x  = (const float*)d_in[0];
    const unsigned int* ei = (const unsigned int*)d_in[1];
    const float* W1 = (const float*)d_in[2];
    const float* b1 = (const float*)d_in[3];
    const float* W2 = (const float*)d_in[4];
    const float* b2 = (const float*)d_in[5];
    float* out = (float*)d_out;

    char* ws = (char*)d_ws;
    size_t off = 0;
    auto take = [&](size_t bytes) {
        char* p = ws + off;
        off += (bytes + 255) & ~(size_t)255;
        return p;
    };
    int*    flag     = (int*)   take(256);
    int*    esrc     = (int*)   take((size_t)N_EDGES * 4);
    int*    rank     = (int*)   take((size_t)N_EDGES * 4);
    int*    deg      = (int*)   take((size_t)N_NODES * 4);
    int*    rowstart = (int*)   take((size_t)(N_NODES + 1) * 4);
    int*    blksum   = (int*)   take((size_t)NB1 * 4);
    int*    blkoff   = (int*)   take((size_t)NB1 * 4);
    float*  dinv     = (float*) take((size_t)N_NODES * 4);
    __half* hs1h     = (__half*)take((size_t)N_NODES * C_HID * 2);
    __half* hs2h     = (__half*)take((size_t)N_NODES * C_OUT * 2);

    // Rank pass: degree histogram + per-edge rank in one atomic sweep
    k_detect<<<1, 64, 0, stream>>>(ei, flag);
    hipMemsetAsync(deg, 0, (size_t)N_NODES * 4, stream);
    k_rank<<<1024, 256, 0, stream>>>(ei, flag, deg, rank);

    // CSR offsets: scan degrees (+ dinv)
    k_scan1<<<NB1, 256, 0, stream>>>(deg, rowstart, blksum, dinv);
    k_scan2<<<1, 512, 0, stream>>>(blksum, blkoff);
    k_scan3<<<NB1, 256, 0, stream>>>(rowstart, blkoff);

    // Atomic-free fill with non-temporal scatter stores
    k_fill2<<<1024, 256, 0, stream>>>(ei, flag, rowstart, rank, esrc);

    // Layer 1 GEMM
    k_gemm1<<<GT_BLOCKS, 256, 0, stream>>>(x, W1, dinv, hs1h);

    // Fused: agg1 + epilogue1 + gemm2  (y1 never hits global memory)
    k_agg1g2<<<AGG1_BLOCKS, 256, 0, stream>>>(rowstart, esrc, hs1h, dinv, b1, W2, hs2h);

    // Layer 2 aggregation + epilogue
    k_agg2<<<N_NODES / 4, 256, 0, stream>>>(rowstart, esrc, hs2h, dinv, b2, out);
}

// Round 10
// 272.559 us; speedup vs baseline: 2.3157x; 1.0707x over previous
//
#include <hip/hip_runtime.h>
#include <hip/hip_fp16.h>

#define N_NODES 100000
#define N_EDGES 1000000
#define C_IN 128
#define C_HID 64
#define C_OUT 32
#define NB1 ((N_NODES + 255) / 256)      // 391 scan blocks
#define GT_BLOCKS 1563                   // gemm1 tiles of 64 rows (ceil(1e5/64))
#define RG_RANK_BLOCKS 781               // rank blocks inside k_rg1
#define RG_GRID 2344                     // 3*781+1: tiles t=2r+m (m<2), rank r (m==2)
#define AGG1_BLOCKS 6250                 // 4 waves/block -> 4 nodes per wave

// ---------------------------------------------------------------------------
// FUSED rank ∥ gemm1 (independent work, co-resident block populations):
//  bid%3==2 -> rank: one atomic pass builds degree histogram + per-edge rank.
//  else     -> gemm tile: hs1h[n][c] = (x[n][:] @ W1)[c], UNSCALED fp16
//              (dinv moved to agg1g2's gather so gemm1 needs no CSR input).
// LDS capped at 32KB (x tile only; W1 via global/L1) -> 5 blocks/CU so the
// rank population keeps enough waves for atomic-latency hiding.
// int64-vs-int32 edge layout detected inline per wave (__all on high dwords).
// ---------------------------------------------------------------------------
__global__ __launch_bounds__(256) void k_rg1(const unsigned int* __restrict__ ei,
                                             int* __restrict__ deg,
                                             int* __restrict__ rank,
                                             const float* __restrict__ x,
                                             const float* __restrict__ W1,
                                             __half* __restrict__ hs1h) {
    __shared__ float xt[64 * C_IN];     // 32 KB
    const int bid = blockIdx.x;
    const int m = bid % 3;
    const int r = bid / 3;

    if (m == 2) {
        // ----- rank block r of RG_RANK_BLOCKS -----
        const bool is64 = __all(ei[2 * (threadIdx.x & 63) + 1] == 0u);
        const int T = RG_RANK_BLOCKS * 256;
        const int t = r * 256 + threadIdx.x;
        int d[6];
#pragma unroll
        for (int i = 0; i < 6; ++i) {
            int e = t + i * T;
            if (e < N_EDGES)
                d[i] = is64 ? ((const int2*)ei)[(size_t)N_EDGES + e].x
                            : (int)ei[(size_t)N_EDGES + e];
        }
        int rk[6];
#pragma unroll
        for (int i = 0; i < 6; ++i) {
            int e = t + i * T;
            if (e < N_EDGES) rk[i] = atomicAdd(&deg[d[i]], 1);
        }
#pragma unroll
        for (int i = 0; i < 6; ++i) {
            int e = t + i * T;
            if (e < N_EDGES) __builtin_nontemporal_store(rk[i], &rank[e]);
        }
        return;
    }

    // ----- gemm tile t = 2r+m of GT_BLOCKS -----
    const int tile = 2 * r + m;
    if (tile >= GT_BLOCKS) return;
    const int t = threadIdx.x;
    {
        const float4* x4g = (const float4*)x;
        float4* xt4w = (float4*)xt;
        const size_t base = (size_t)tile * 64 * (C_IN / 4);
        const size_t xmax = (size_t)N_NODES * (C_IN / 4) - 1;
#pragma unroll
        for (int j = 0; j < 8; ++j) {
            size_t idx = base + t + j * 256;
            if (idx > xmax) idx = xmax;            // tail clamp (dup reads ok)
            xt4w[t + j * 256] = x4g[idx];
        }
    }
    __syncthreads();
    const int c2 = t & 31;          // channel pair
    const int h  = (t >> 5) & 1;    // half-wave -> row group
    const int wid = t >> 6;
    const int lrow0 = wid * 16 + h * 8;
    const int grow0 = tile * 64 + lrow0;
    const float4* xt4 = (const float4*)xt;

    float acc0[8] = {0, 0, 0, 0, 0, 0, 0, 0};
    float acc1[8] = {0, 0, 0, 0, 0, 0, 0, 0};
#pragma unroll 2
    for (int k4 = 0; k4 < C_IN / 4; ++k4) {
        float4 xv[8];
#pragma unroll
        for (int rr = 0; rr < 8; ++rr)
            xv[rr] = xt4[(lrow0 + rr) * (C_IN / 4) + k4];   // LDS broadcast
        float2 wv[4];
#pragma unroll
        for (int j = 0; j < 4; ++j)
            wv[j] = *reinterpret_cast<const float2*>(&W1[(k4 * 4 + j) * C_HID + 2 * c2]);
#pragma unroll
        for (int rr = 0; rr < 8; ++rr) {
            acc0[rr] = fmaf(xv[rr].x, wv[0].x, acc0[rr]);
            acc1[rr] = fmaf(xv[rr].x, wv[0].y, acc1[rr]);
            acc0[rr] = fmaf(xv[rr].y, wv[1].x, acc0[rr]);
            acc1[rr] = fmaf(xv[rr].y, wv[1].y, acc1[rr]);
            acc0[rr] = fmaf(xv[rr].z, wv[2].x, acc0[rr]);
            acc1[rr] = fmaf(xv[rr].z, wv[2].y, acc1[rr]);
            acc0[rr] = fmaf(xv[rr].w, wv[3].x, acc0[rr]);
            acc1[rr] = fmaf(xv[rr].w, wv[3].y, acc1[rr]);
        }
    }
    __half2* h2o = (__half2*)hs1h;
#pragma unroll
    for (int rr = 0; rr < 8; ++rr) {
        int gr = grow0 + rr;
        if (gr < N_NODES)
            h2o[(size_t)gr * 32 + c2] = __floats2half2_rn(acc0[rr], acc1[rr]);
    }
}

// ---------------------------------------------------------------------------
// 3-kernel exclusive prefix scan of deg -> rowstart; also dinv = rsqrt(deg+1).
// ---------------------------------------------------------------------------
__global__ __launch_bounds__(256) void k_scan1(const int* __restrict__ deg,
                                               int* __restrict__ rowstart,
                                               int* __restrict__ blksum,
                                               float* __restrict__ dinv) {
    __shared__ int sm[256];
    int i = blockIdx.x * 256 + threadIdx.x;
    int v = (i < N_NODES) ? deg[i] : 0;
    if (i < N_NODES) dinv[i] = rsqrtf((float)v + 1.0f);
    sm[threadIdx.x] = v;
    __syncthreads();
    for (int o = 1; o < 256; o <<= 1) {
        int t = (threadIdx.x >= o) ? sm[threadIdx.x - o] : 0;
        __syncthreads();
        sm[threadIdx.x] += t;
        __syncthreads();
    }
    if (i < N_NODES) rowstart[i] = sm[threadIdx.x] - v;   // exclusive, block-local
    if (threadIdx.x == 255) blksum[blockIdx.x] = sm[255];
}

__global__ __launch_bounds__(512) void k_scan2(const int* __restrict__ blksum,
                                               int* __restrict__ blkoff) {
    __shared__ int sm[512];
    int v = (threadIdx.x < NB1) ? blksum[threadIdx.x] : 0;
    sm[threadIdx.x] = v;
    __syncthreads();
    for (int o = 1; o < 512; o <<= 1) {
        int t = (threadIdx.x >= o) ? sm[threadIdx.x - o] : 0;
        __syncthreads();
        sm[threadIdx.x] += t;
        __syncthreads();
    }
    if (threadIdx.x < NB1) blkoff[threadIdx.x] = sm[threadIdx.x] - v;  // exclusive
}

__global__ __launch_bounds__(256) void k_scan3(int* __restrict__ rowstart,
                                               const int* __restrict__ blkoff) {
    int i = blockIdx.x * 256 + threadIdx.x;
    if (i < N_NODES) rowstart[i] += blkoff[i >> 8];
    if (i == 0) rowstart[N_NODES] = N_EDGES;
}

// ---------------------------------------------------------------------------
// Fill pass: p = rowstart[dst] + rank[e]; esrc[p] = src. No atomics; NT store.
// ---------------------------------------------------------------------------
__global__ __launch_bounds__(256) void k_fill2(const unsigned int* __restrict__ ei,
                                               const int* __restrict__ rowstart,
                                               const int* __restrict__ rank,
                                               int* __restrict__ esrc) {
    const bool is64 = __all(ei[2 * (threadIdx.x & 63) + 1] == 0u);
    const int T = gridDim.x * 256;
    const int t = blockIdx.x * 256 + threadIdx.x;
#pragma unroll
    for (int i = 0; i < 4; ++i) {
        int e = t + i * T;
        if (e < N_EDGES) {
            int s, d;
            if (is64) {
                s = ((const int2*)ei)[e].x;
                d = ((const int2*)ei)[(size_t)N_EDGES + e].x;
            } else {
                s = (int)ei[e];
                d = (int)ei[(size_t)N_EDGES + e];
            }
            int p = rowstart[d] + rank[e];
            __builtin_nontemporal_store(s, &esrc[p]);
        }
    }
}

// ---------------------------------------------------------------------------
// FUSED agg1 + layer-1 epilogue + GEMM2 (y never leaves the CU):
//   y = relu(dv*(Σ dinv[src]*h[src] + dv*h[n]) + b1);  hs2h[n] = (y@W2)*dv
// hs1h is UNSCALED h; per-edge dinv[src] gathered (400KB, L2-resident) and
// applied via fmaf -- predication by clamping ds to 0 (cheaper than cndmask
// per channel). Wave = 1 node/iter, 2 half-waves x 8 slots = 16 edges/iter.
// ---------------------------------------------------------------------------
__global__ __launch_bounds__(256) void k_agg1g2(const int* __restrict__ rowstart,
                                                const int* __restrict__ esrc,
                                                const __half* __restrict__ hs1h,
                                                const float* __restrict__ dinv,
                                                const float* __restrict__ b1,
                                                const float* __restrict__ W2,
                                                __half* __restrict__ hs2h) {
    __shared__ float2 yrow[4][32];      // per-wave y-row buffer
    const int wid = threadIdx.x >> 6;
    const int lane = threadIdx.x & 63;
    const int c2 = lane & 31;           // layer1 channel-pair; layer2 out-channel
    const int eo = lane >> 5;           // half-wave index
    float Wreg[32];
#pragma unroll
    for (int kk = 0; kk < 16; ++kk) {
        Wreg[2 * kk]     = W2[(32 * eo + 2 * kk) * C_OUT + c2];
        Wreg[2 * kk + 1] = W2[(32 * eo + 2 * kk + 1) * C_OUT + c2];
    }
    const __half2* h2 = (const __half2*)hs1h;
    const float2 bb = { b1[2 * c2], b1[2 * c2 + 1] };
    const int waveId = blockIdx.x * 4 + wid;

    for (int node = waveId; node < N_NODES; node += AGG1_BLOCKS * 4) {
        const int beg = rowstart[node], end = rowstart[node + 1];
        float2 acc; acc.x = 0.f; acc.y = 0.f;
        for (int j0 = beg; j0 < end; j0 += 16) {
            const int jj = j0 + eo;
            int idx[8];
#pragma unroll
            for (int s = 0; s < 8; ++s) {
                int j = jj + 2 * s;
                idx[s] = esrc[j < end ? j : beg];   // clamp: dup load, L1 hit
            }
            float ds[8];
#pragma unroll
            for (int s = 0; s < 8; ++s)
                ds[s] = (jj + 2 * s < end) ? dinv[idx[s]] : 0.f;  // predicate via 0-scale
            float2 v[8];
#pragma unroll
            for (int s = 0; s < 8; ++s)
                v[s] = __half22float2(h2[(size_t)idx[s] * 32 + c2]);
#pragma unroll
            for (int s = 0; s < 8; ++s) {
                acc.x = fmaf(ds[s], v[s].x, acc.x);
                acc.y = fmaf(ds[s], v[s].y, acc.y);
            }
        }
        acc.x += __shfl_xor(acc.x, 32);
        acc.y += __shfl_xor(acc.y, 32);
        // layer-1 epilogue: y = relu(dv*(acc + dv*self) + b)
        const float dv = dinv[node];
        float2 self = __half22float2(h2[(size_t)node * 32 + c2]);
        float2 y;
        y.x = fmaxf(fmaf(dv, fmaf(dv, self.x, acc.x), bb.x), 0.f);
        y.y = fmaxf(fmaf(dv, fmaf(dv, self.y, acc.y), bb.y), 0.f);
        yrow[wid][c2] = y;              // both halves write same value (benign)
        __builtin_amdgcn_wave_barrier();
        // layer-2 matvec: out[c2] = Σ_k y[k] * W2[k][c2], k-half per eo
        float o = 0.f;
#pragma unroll
        for (int kk = 0; kk < 16; ++kk) {
            float2 yv = yrow[wid][16 * eo + kk];
            o = fmaf(yv.x, Wreg[2 * kk], o);
            o = fmaf(yv.y, Wreg[2 * kk + 1], o);
        }
        __builtin_amdgcn_wave_barrier();
        o += __shfl_xor(o, 32);
        if (eo == 0)
            hs2h[(size_t)node * C_OUT + c2] = __float2half(o * dv);
    }
}

// ---------------------------------------------------------------------------
// Agg2 (+fused epilogue, no relu): out = dinv*(Σ hs2[src] + hs2[n]) + b2
// hs2h already dinv-scaled by producer. 4 quarter-waves x 4 slots.
// ---------------------------------------------------------------------------
__global__ __launch_bounds__(256) void k_agg2(const int* __restrict__ rowstart,
                                              const int* __restrict__ esrc,
                                              const __half* __restrict__ hs2h,
                                              const float* __restrict__ dinv,
                                              const float* __restrict__ b2,
                                              float* __restrict__ out) {
    const int node = blockIdx.x * 4 + (threadIdx.x >> 6);
    const int lane = threadIdx.x & 63;
    const int c2 = lane & 15;
    const int eo = lane >> 4;
    const __half2* h2 = (const __half2*)hs2h;
    const int beg = rowstart[node], end = rowstart[node + 1];
    float2 acc; acc.x = 0.f; acc.y = 0.f;
    for (int j0 = beg; j0 < end; j0 += 16) {
        const int jj = j0 + eo;
        int idx[4];
#pragma unroll
        for (int s = 0; s < 4; ++s) {
            int j = jj + 4 * s;
            idx[s] = esrc[j < end ? j : beg];
        }
        float2 v[4];
#pragma unroll
        for (int s = 0; s < 4; ++s)
            v[s] = __half22float2(h2[(size_t)idx[s] * 16 + c2]);
#pragma unroll
        for (int s = 0; s < 4; ++s) {
            if (jj + 4 * s < end) { acc.x += v[s].x; acc.y += v[s].y; }
        }
    }
    acc.x += __shfl_xor(acc.x, 16);
    acc.y += __shfl_xor(acc.y, 16);
    acc.x += __shfl_xor(acc.x, 32);
    acc.y += __shfl_xor(acc.y, 32);
    if (eo == 0) {
        float2 self = __half22float2(h2[(size_t)node * 16 + c2]);
        float dv = dinv[node];
        float2 o;
        o.x = fmaf(dv, acc.x + self.x, b2[2 * c2]);
        o.y = fmaf(dv, acc.y + self.y, b2[2 * c2 + 1]);
        reinterpret_cast<float2*>(out)[(size_t)node * 16 + c2] = o;
    }
}

extern "C" void kernel_launch(void* const* d_in, const int* in_sizes, int n_in,
                              void* d_out, int out_size, void* d_ws, size_t ws_size,
                              hipStream_t stream) {
    const float* x  = (const float*)d_in[0];
    const unsigned int* ei = (const unsigned int*)d_in[1];
    const float* W1 = (const float*)d_in[2];
    const float* b1 = (const float*)d_in[3];
    const float* W2 = (const float*)d_in[4];
    const float* b2 = (const float*)d_in[5];
    float* out = (float*)d_out;

    char* ws = (char*)d_ws;
    size_t off = 0;
    auto take = [&](size_t bytes) {
        char* p = ws + off;
        off += (bytes + 255) & ~(size_t)255;
        return p;
    };
    int*    esrc     = (int*)   take((size_t)N_EDGES * 4);
    int*    rank     = (int*)   take((size_t)N_EDGES * 4);
    int*    deg      = (int*)   take((size_t)N_NODES * 4);
    int*    rowstart = (int*)   take((size_t)(N_NODES + 1) * 4);
    int*    blksum   = (int*)   take((size_t)NB1 * 4);
    int*    blkoff   = (int*)   take((size_t)NB1 * 4);
    float*  dinv     = (float*) take((size_t)N_NODES * 4);
    __half* hs1h     = (__half*)take((size_t)N_NODES * C_HID * 2);
    __half* hs2h     = (__half*)take((size_t)N_NODES * C_OUT * 2);

    // rank ∥ gemm1 (independent; co-resident block populations)
    hipMemsetAsync(deg, 0, (size_t)N_NODES * 4, stream);
    k_rg1<<<RG_GRID, 256, 0, stream>>>(ei, deg, rank, x, W1, hs1h);

    // CSR offsets: scan degrees (+ dinv)
    k_scan1<<<NB1, 256, 0, stream>>>(deg, rowstart, blksum, dinv);
    k_scan2<<<1, 512, 0, stream>>>(blksum, blkoff);
    k_scan3<<<NB1, 256, 0, stream>>>(rowstart, blkoff);

    // Atomic-free fill with non-temporal scatter stores
    k_fill2<<<1024, 256, 0, stream>>>(ei, rowstart, rank, esrc);

    // Fused: agg1 + epilogue1 + gemm2  (y1 never hits global memory)
    k_agg1g2<<<AGG1_BLOCKS, 256, 0, stream>>>(rowstart, esrc, hs1h, dinv, b1, W2, hs2h);

    // Layer 2 aggregation + epilogue
    k_agg2<<<N_NODES / 4, 256, 0, stream>>>(rowstart, esrc, hs2h, dinv, b2, out);
}